// Round 14
// baseline (142.252 us; speedup 1.0000x reference)
//
#include <hip/hip_runtime.h>
#include <math.h>

// Problem constants
#define KTOP_ 716
#define SCALE_ 0.125f
#define QSCALE_ 0.1803368801111731f   // 0.125 * log2(e): softmax in exp2 domain
#define LN2_ 0.6931471805599453f

#define WAIT_VMCNT(n) asm volatile("s_waitcnt vmcnt(" #n ")" ::: "memory")
static __device__ inline void SBAR() {
  __builtin_amdgcn_sched_barrier(0);
  __builtin_amdgcn_s_barrier();
  __builtin_amdgcn_sched_barrier(0);
}

typedef float f4v __attribute__((ext_vector_type(4)));
typedef short s8v __attribute__((ext_vector_type(8)));
typedef __bf16 bf8v __attribute__((ext_vector_type(8)));

static __device__ inline unsigned short f2bf(float f) {
  unsigned u = __float_as_uint(f);
  u += 0x7fffu + ((u >> 16) & 1u);
  return (unsigned short)(u >> 16);
}
static __device__ inline unsigned short f2bfn(float f) {
  union { __bf16 b; unsigned short u; } cv;
  cv.b = (__bf16)f;           // compiler emits v_cvt_pk_bf16_f32 for pairs
  return cv.u;
}
static __device__ inline float bf2f(unsigned short h) {
  return __uint_as_float((unsigned)h << 16);
}
static __device__ inline f4v mfma16(s8v a, s8v b, f4v c) {
  union { s8v s; bf8v b; } ua, ub;
  ua.s = a; ub.s = b;
  return __builtin_amdgcn_mfma_f32_16x16x32_bf16(ua.b, ub.b, c, 0, 0, 0);
}
static __device__ inline void gload16(const unsigned short* g, unsigned short* lbase) {
  __builtin_amdgcn_global_load_lds(
      (const __attribute__((address_space(1))) unsigned int*)g,
      (__attribute__((address_space(3))) unsigned int*)lbase, 16, 0, 0);
}

// ---------------------------------------------------------------------------
// pool1 (fused: also emits xs = bf16 of x); partial sums/maxes to ppsum/ppmax
// ---------------------------------------------------------------------------
__global__ __launch_bounds__(256) void pool1(const float* __restrict__ x,
                                             float* __restrict__ psum,
                                             float* __restrict__ pmax,
                                             unsigned short* __restrict__ xs) {
  int bid = blockIdx.x;            // b*64 + sl
  int b = bid >> 6, sl = bid & 63;
  int t = threadIdx.x;
  float s[4] = {0.f, 0.f, 0.f, 0.f};
  float m[4] = {-INFINITY, -INFINITY, -INFINITY, -INFINITY};
  const float* xb = x + ((size_t)b << 20) + (size_t)sl * 16 * 1024;
  unsigned short* xo = xs + ((size_t)(b * 1024 + sl * 16)) * 1024;
  for (int l = 0; l < 16; ++l) {
    #pragma unroll
    for (int dg = 0; dg < 4; ++dg) {
      float v = xb[l * 1024 + dg * 256 + t];
      s[dg] += v;
      m[dg] = fmaxf(m[dg], v);
      xo[(size_t)l * 1024 + dg * 256 + t] = f2bfn(v);
    }
  }
  #pragma unroll
  for (int dg = 0; dg < 4; ++dg) {
    psum[(size_t)bid * 1024 + dg * 256 + t] = s[dg];
    pmax[(size_t)bid * 1024 + dg * 256 + t] = m[dg];
  }
}

// ---------------------------------------------------------------------------
// ps_gemv1 (fused pool2)
// ---------------------------------------------------------------------------
__global__ __launch_bounds__(256) void ps_gemv1(const float* __restrict__ psum,
                                                const float* __restrict__ pmax,
                                                const float* __restrict__ w1,
                                                const float* __restrict__ b1,
                                                float* __restrict__ h1) {
  __shared__ float pool_s[1024];
  int bid = blockIdx.x;            // b*16 + og
  int b = bid >> 4, og = bid & 15;
  int t = threadIdx.x;
  #pragma unroll
  for (int i = 0; i < 4; ++i) {
    int d = t + 256 * i;
    float s = 0.f, m = -INFINITY;
    #pragma unroll 8
    for (int sl = 0; sl < 64; ++sl) {
      s += psum[((size_t)b * 64 + sl) * 1024 + d];
      m = fmaxf(m, pmax[((size_t)b * 64 + sl) * 1024 + d]);
    }
    pool_s[d] = (s * (1.0f / 1024.0f) + m) * 0.5f;
  }
  __syncthreads();
  int ol = t >> 2, ks = t & 3;
  int o = og * 64 + ol;
  const float4* wr = (const float4*)(w1 + (size_t)o * 1024 + ks * 256);
  const float4* pp = (const float4*)(&pool_s[ks * 256]);
  float acc = 0.f;
  #pragma unroll 8
  for (int j = 0; j < 64; ++j) {
    float4 a = wr[j], p = pp[j];
    acc += a.x * p.x + a.y * p.y + a.z * p.z + a.w * p.w;
  }
  acc += __shfl_xor(acc, 1, 64);
  acc += __shfl_xor(acc, 2, 64);
  if (ks == 0) h1[b * 1024 + o] = acc + b1[o];
}

// ---------------------------------------------------------------------------
// ps_gemv2 (fused LN)
// ---------------------------------------------------------------------------
__global__ __launch_bounds__(256) void ps_gemv2(const float* __restrict__ h1,
                                                const float* __restrict__ lng,
                                                const float* __restrict__ lnb,
                                                const float* __restrict__ w2,
                                                const float* __restrict__ b2,
                                                float* __restrict__ h2) {
  __shared__ float hs[1024];
  __shared__ float red[256];
  int bid = blockIdx.x;            // b*8 + og
  int b = bid >> 3, og = bid & 7;
  int t = threadIdx.x;
  const float* hb = h1 + b * 1024;
  float v0[4];
  float ls = 0.f;
  #pragma unroll
  for (int i = 0; i < 4; ++i) { v0[i] = hb[t + 256 * i]; ls += v0[i]; }
  red[t] = ls; __syncthreads();
  for (int s = 128; s > 0; s >>= 1) { if (t < s) red[t] += red[t + s]; __syncthreads(); }
  float mean = red[0] * (1.0f / 1024.0f);
  __syncthreads();
  float lq = 0.f;
  #pragma unroll
  for (int i = 0; i < 4; ++i) { float dv = v0[i] - mean; lq += dv * dv; }
  red[t] = lq; __syncthreads();
  for (int s = 128; s > 0; s >>= 1) { if (t < s) red[t] += red[t + s]; __syncthreads(); }
  float rstd = 1.0f / sqrtf(red[0] * (1.0f / 1024.0f) + 1e-5f);
  #pragma unroll
  for (int i = 0; i < 4; ++i) {
    float v = (v0[i] - mean) * rstd * lng[t + 256 * i] + lnb[t + 256 * i];
    hs[t + 256 * i] = 0.5f * v * (1.0f + erff(v * 0.70710678118654752f));
  }
  __syncthreads();
  int ol = t >> 2, ks = t & 3;
  int o = og * 64 + ol;
  const float4* wr = (const float4*)(w2 + (size_t)o * 1024 + ks * 256);
  const float4* pp = (const float4*)(&hs[ks * 256]);
  float acc = 0.f;
  #pragma unroll 8
  for (int j = 0; j < 64; ++j) {
    float4 a = wr[j], p = pp[j];
    acc += a.x * p.x + a.y * p.y + a.z * p.z + a.w * p.w;
  }
  acc += __shfl_xor(acc, 1, 64);
  acc += __shfl_xor(acc, 2, 64);
  if (ks == 0) {
    float v = acc + b2[o];
    h2[b * 512 + o] = 0.5f * v * (1.0f + erff(v * 0.70710678118654752f));
  }
}

__global__ __launch_bounds__(256) void ps_logits(const float* __restrict__ h2,
                                                 const float* __restrict__ w3,
                                                 const float* __restrict__ b3,
                                                 const float* __restrict__ pb,
                                                 int* __restrict__ meta) {
  __shared__ float red[256];
  int b = blockIdx.x, t = threadIdx.x;
  float lgv[3];
  for (int c = 0; c < 3; ++c) {
    float p = 0.f;
    for (int i = t; i < 512; i += 256) p += h2[b * 512 + i] * w3[c * 512 + i];
    red[t] = p; __syncthreads();
    for (int s = 128; s > 0; s >>= 1) { if (t < s) red[t] += red[t + s]; __syncthreads(); }
    lgv[c] = red[0] + b3[c] + pb[c];
    __syncthreads();
  }
  if (t == 0) {
    float mx = fmaxf(lgv[0], fmaxf(lgv[1], lgv[2]));
    float e0 = __expf(lgv[0] - mx), e1 = __expf(lgv[1] - mx), e2 = __expf(lgv[2] - mx);
    float inv = 1.0f / (e0 + e1 + e2);
    float p0 = e0 * inv, p1 = e1 * inv, p2 = e2 * inv;
    float c00 = p1;
    float c10 = p0 + p1;
    float c01 = p1 + p2;
    float c11 = (p0 + p1) + p2;
    int t00 = c00 > 0.1f, t10 = c10 > 0.1f, t01 = c01 > 0.1f, t11 = c11 > 0.1f;
    meta[b * 8 + 0] = t00;
    meta[b * 8 + 1] = t10;
    meta[b * 8 + 2] = t01;
    meta[b * 8 + 3] = t11;
    meta[b * 8 + 4] = (t00 != t01) || (t10 != t11);
  }
}

// ---------------------------------------------------------------------------
// prep_w: both weight matrices -> bf16 in one launch
// ---------------------------------------------------------------------------
__global__ __launch_bounds__(256) void prep_w(const float* __restrict__ w_qkv,
                                              const float* __restrict__ w_proj,
                                              unsigned short* __restrict__ wqs,
                                              unsigned short* __restrict__ wps) {
  int i = blockIdx.x * 256 + threadIdx.x;
  const float* src;
  unsigned short* dst;
  int idx;
  if (i < 786432) { src = w_qkv; dst = wqs; idx = i; }
  else            { src = w_proj; dst = wps; idx = i - 786432; }
  float4 v = ((const float4*)src)[idx];
  ushort4 o;
  o.x = f2bfn(v.x); o.y = f2bfn(v.y); o.z = f2bfn(v.z); o.w = f2bfn(v.w);
  *(ushort4*)(dst + (size_t)idx * 4) = o;
}

// ---------------------------------------------------------------------------
// gemm_sp<MODE,TM,TN>: C[M][N] = A[M][1024].B[N][1024] (bf16, K=1024)
// counted-vmcnt pipeline, named double buffers, XOR-swizzled LDS.
// MODE 0 (128x192): grid 512 = one residency round (no tail); c per frag.
// MODE 1 (64x128): out = C + bias.
// ---------------------------------------------------------------------------
template <int MODE, int TM, int TN>
__global__ __launch_bounds__(256) void gemm_sp(
    const unsigned short* __restrict__ A, const unsigned short* __restrict__ B,
    const float* __restrict__ bias,
    unsigned short* __restrict__ qxo, unsigned short* __restrict__ kxo,
    unsigned short* __restrict__ vxo,
    float* __restrict__ out, int Nb) {
  constexpr int MFR = TM / 32;               // m-frags per wave
  constexpr int NFR = TN / 32;               // n-frags per wave
  __shared__ unsigned short AsmA[TM * 64];
  __shared__ unsigned short AsmB[TM * 64];
  __shared__ unsigned short BsmA[TN * 64];
  __shared__ unsigned short BsmB[TN * 64];

  int bid = blockIdx.x;
  int bm, bn;
  if (MODE == 0) {
    // 512 blocks: 8 XCDs x 64; per XCD 8 rows x 8 cols, r fastest (~2.8MB L2)
    int xcd = bid & 7, idx = bid >> 3;       // idx 0..63
    bm = (xcd >> 1) * 8 + (idx & 7);
    bn = (xcd & 1) * 8 + (idx >> 3);
  } else {
    int cpx = gridDim.x >> 3;
    int g = (bid & 7) * cpx + (bid >> 3);
    bm = g / Nb; bn = g % Nb;
  }
  size_t row0 = (size_t)bm * TM, col0 = (size_t)bn * TN;

  int tid = threadIdx.x, lane = tid & 63, wv = tid >> 6;
  int wm = (wv >> 1) * (MFR * 16), wn = (wv & 1) * (NFR * 16);
  int rowg = lane >> 4, colc = lane & 15;

  f4v acc[MFR][NFR];
  #pragma unroll
  for (int mf = 0; mf < MFR; ++mf)
    #pragma unroll
    for (int nf = 0; nf < NFR; ++nf) acc[mf][nf] = (f4v){0.f, 0.f, 0.f, 0.f};

  const unsigned short* Abase = A + row0 * 1024;
  const unsigned short* Bbase = B + col0 * 1024;

  auto STAGE = [&](int kb, unsigned short* Ad, unsigned short* Bd) {
    #pragma unroll
    for (int p = 0; p < TM / 32; ++p) {
      int idx = p * 256 + tid;
      int row = idx >> 3;
      int sc = (idx & 7) ^ (row & 7);
      gload16(Abase + (size_t)row * 1024 + kb + sc * 8,
              Ad + (size_t)(p * 256 + wv * 64) * 8);
    }
    #pragma unroll
    for (int p = 0; p < TN / 32; ++p) {
      int idx = p * 256 + tid;
      int row = idx >> 3;
      int sc = (idx & 7) ^ (row & 7);
      gload16(Bbase + (size_t)row * 1024 + kb + sc * 8,
              Bd + (size_t)(p * 256 + wv * 64) * 8);
    }
  };

  auto COMPUTE = [&](const unsigned short* Ab, const unsigned short* Bb) {
    #pragma unroll
    for (int ks = 0; ks < 2; ++ks) {
      s8v af[MFR], bf_[NFR];
      #pragma unroll
      for (int mf = 0; mf < MFR; ++mf) {
        int row = wm + mf * 16 + colc;
        int kby = (ks * 64 + rowg * 16) ^ ((row & 7) << 4);
        af[mf] = *(const s8v*)((const char*)Ab + row * 128 + kby);
      }
      #pragma unroll
      for (int nf = 0; nf < NFR; ++nf) {
        int row = wn + nf * 16 + colc;
        int kby = (ks * 64 + rowg * 16) ^ ((row & 7) << 4);
        bf_[nf] = *(const s8v*)((const char*)Bb + row * 128 + kby);
      }
      __builtin_amdgcn_s_setprio(1);
      #pragma unroll
      for (int mf = 0; mf < MFR; ++mf)
        #pragma unroll
        for (int nf = 0; nf < NFR; ++nf)
          acc[mf][nf] = mfma16(af[mf], bf_[nf], acc[mf][nf]);
      __builtin_amdgcn_s_setprio(0);
    }
  };

  constexpr int NLD = TM / 32 + TN / 32;     // loads per STAGE per thread

  STAGE(0, AsmA, BsmA);
  for (int kb = 0; kb < 1024; kb += 128) {
    STAGE(kb + 64, AsmB, BsmB);
    if constexpr (NLD == 10) WAIT_VMCNT(10); else WAIT_VMCNT(6);
    SBAR();
    COMPUTE(AsmA, BsmA);
    SBAR();
    if (kb + 128 < 1024) {
      STAGE(kb + 128, AsmA, BsmA);
      if constexpr (NLD == 10) WAIT_VMCNT(10); else WAIT_VMCNT(6);
    } else {
      WAIT_VMCNT(0);
    }
    SBAR();
    COMPUTE(AsmB, BsmB);
    SBAR();
  }

  if (MODE == 0) {
    #pragma unroll
    for (int mf = 0; mf < MFR; ++mf) {
      int m0 = (int)row0 + wm + mf * 16 + rowg * 4;
      int bb = m0 >> 10, l0 = m0 & 1023;   // l0 % 4 == 0, 4 consecutive l
      #pragma unroll
      for (int nf = 0; nf < NFR; ++nf) {
        int n = (int)col0 + wn + nf * 16 + colc;
        int c = n >> 10;                    // per-frag: 16-wide never straddles
        int hh = (n >> 6) & 15, hd = n & 63;
        int bhl = bb * 16 + hh;
        if (c == 2) {
          ushort4 h4;
          h4.x = f2bfn(acc[mf][nf][0]);
          h4.y = f2bfn(acc[mf][nf][1]);
          h4.z = f2bfn(acc[mf][nf][2]);
          h4.w = f2bfn(acc[mf][nf][3]);
          *(ushort4*)(vxo + ((size_t)bhl * 64 + hd) * 1024 + l0) = h4;
        } else {
          unsigned short* dst = ((c == 0) ? qxo : kxo) +
                                ((size_t)bhl * 1024 + l0) * 64 + hd;
          float sc_ = (c == 0) ? QSCALE_ : 1.0f;
          #pragma unroll
          for (int r = 0; r < 4; ++r)
            dst[(size_t)r * 64] = f2bfn(acc[mf][nf][r] * sc_);
        }
      }
    }
  } else {
    #pragma unroll
    for (int mf = 0; mf < MFR; ++mf) {
      #pragma unroll
      for (int r = 0; r < 4; ++r) {
        int m = (int)row0 + wm + mf * 16 + rowg * 4 + r;
        #pragma unroll
        for (int nf = 0; nf < NFR; ++nf) {
          int n = (int)col0 + wn + nf * 16 + colc;
          out[(size_t)m * 1024 + n] = acc[mf][nf][r] + bias[n];
        }
      }
    }
  }
}

// ---------------------------------------------------------------------------
// attn_flash v9: KVBLK=128 (8 j-tiles -> half the barriers/waits/softmax
// reductions). 512 threads / 8 waves / 128 q-rows; counted vmcnt; named
// buffers; V tiles 16-slot XOR swizzle; px reused per 64-j half (wave-private).
// ---------------------------------------------------------------------------
__global__ __launch_bounds__(512) void attn_flash(
    const unsigned short* __restrict__ qx, const unsigned short* __restrict__ kx,
    const unsigned short* __restrict__ vx, const int* __restrict__ meta,
    unsigned short* __restrict__ ao) {
  int n = blockIdx.x;                    // 512 blocks: 64 bh x 8 qt2
  int bh = ((n & 7) << 3) | (n >> 6);    // XCD swizzle (bijective)
  int qt2 = (n >> 3) & 7;
  int b = bh >> 4, h = bh & 15;
  const int* mb = meta + b * 8;
  if (mb[4]) return;  // sparse regime -> attn_sparse owns this batch
  int t00 = mb[0], t10 = mb[1];

  int tid = threadIdx.x, lane = tid & 63, wv = tid >> 6;
  int g = lane >> 4, colc = lane & 15;
  int bq0 = qt2 * 128;
  int q0 = bq0 + wv * 16;

  if (!t10) {
    // self-only: out row = v row (cold path; vx is transposed [d][l])
    #pragma unroll
    for (int it = 0; it < 4; ++it) {
      int idx = tid + it * 512;
      int r = idx >> 4, dc = (idx & 15) * 4;
      ushort4 o;
      unsigned short* op = (unsigned short*)&o;
      #pragma unroll
      for (int j = 0; j < 4; ++j)
        op[j] = vx[((size_t)bh * 64 + dc + j) * 1024 + bq0 + r];
      *(ushort4*)(ao + ((size_t)b * 1024 + bq0 + r) * 1024 + h * 64 + dc) = o;
    }
    return;
  }
  bool local_only = !t00;

  __shared__ __align__(16) unsigned short KsmA[128 * 64];   // 128 j x 64 d
  __shared__ __align__(16) unsigned short KsmB[128 * 64];
  __shared__ __align__(16) unsigned short VsmA[64 * 128];   // 64 d x 128 j
  __shared__ __align__(16) unsigned short VsmB[64 * 128];
  __shared__ __align__(16) unsigned short px[8][16][64];    // per-wave, reused

  // Q fragments (B operand: row=i=colc, 2 k-steps cover K=64)
  const unsigned short* qb = qx + ((size_t)bh * 1024 + q0 + colc) * 64 + g * 8;
  s8v Q0 = *(const s8v*)(qb);
  s8v Q1 = *(const s8v*)(qb + 32);

  f4v O[4];
  #pragma unroll
  for (int df = 0; df < 4; ++df) O[df] = (f4v){0.f, 0.f, 0.f, 0.f};
  float m = -1e30f, lsum = 0.f;   // per-lane: row i = q0+colc

  const unsigned short* kxb = kx + ((size_t)bh << 10) * 64;
  const unsigned short* vxb = vx + ((size_t)bh << 16);

  int jt_lo = 0, jt_hi = 7;
  if (local_only) {
    int lo = (bq0 - 16) >> 7, hi = (bq0 + 143) >> 7;
    jt_lo = lo < 0 ? 0 : lo;
    jt_hi = hi > 7 ? 7 : hi;
  }

  auto STAGE = [&](int jt, unsigned short* Kd, unsigned short* Vd) {
    int jc = jt << 7;
    #pragma unroll
    for (int p = 0; p < 2; ++p) {
      int cidx = p * 512 + tid;
      // K: 128 rows x 128B (8 chunks/row)
      int krow = cidx >> 3;
      int ksc = (cidx & 7) ^ (krow & 7);
      gload16(kxb + (size_t)(jc + krow) * 64 + ksc * 8,
              Kd + (size_t)(p * 512 + wv * 64) * 8);
      // V: 64 d-rows x 256B (16 chunks/row)
      int vrow = cidx >> 4;
      int vsc = (cidx & 15) ^ (vrow & 15);
      gload16(vxb + (size_t)vrow * 1024 + jc + vsc * 8,
              Vd + (size_t)(p * 512 + wv * 64) * 8);
    }
  };

  int swk = (colc & 7) << 4;       // K read swizzle (j-row & 7 == colc & 7)
  int swv = colc << 4;             // V read swizzle (d-row & 15 == colc)
  int sx = (colc & 7) << 1;        // px slot swizzle

  auto COMPUTE = [&](int jc0, const char* Kb, const char* Vb) {
    if (local_only && (jc0 + 127 < q0 - 16 || jc0 > q0 + 31)) return;
    // ---- S^T: s[jf][r] = S[j=jc0+jf*16+4g+r][i=q0+colc], jf=0..7 ----
    f4v s[8];
    __builtin_amdgcn_s_setprio(1);
    #pragma unroll
    for (int jf = 0; jf < 8; ++jf) {
      const char* kp = Kb + (jf * 16 + colc) * 128;
      s8v K0 = *(const s8v*)(kp + ((g * 16) ^ swk));
      s8v K1 = *(const s8v*)(kp + ((64 + g * 16) ^ swk));
      f4v acc = (f4v){0.f, 0.f, 0.f, 0.f};
      acc = mfma16(K0, Q0, acc);
      acc = mfma16(K1, Q1, acc);
      s[jf] = acc;
    }
    __builtin_amdgcn_s_setprio(0);

    if (local_only) {
      int i = q0 + colc;
      #pragma unroll
      for (int jf = 0; jf < 8; ++jf)
        #pragma unroll
        for (int r = 0; r < 4; ++r) {
          int j = jc0 + jf * 16 + 4 * g + r;
          int dj = i - j;
          if (dj > 16 || dj < -16) s[jf][r] = -1e30f;
        }
    }

    // ---- per-row (per-lane) chunk max over 32 values ----
    float cm = -1e30f;
    #pragma unroll
    for (int jf = 0; jf < 8; ++jf)
      #pragma unroll
      for (int r = 0; r < 4; ++r) cm = fmaxf(cm, s[jf][r]);
    cm = fmaxf(cm, __shfl_xor(cm, 16, 64));
    cm = fmaxf(cm, __shfl_xor(cm, 32, 64));

    // T13 defer-rescale
    if (__any(cm > m + 8.0f)) {
      float mn = fmaxf(m, cm);
      float fac = __builtin_amdgcn_exp2f(m - mn);
      m = mn;
      lsum *= fac;
      float fo[4];
      #pragma unroll
      for (int r = 0; r < 4; ++r)
        fo[r] = __shfl(fac, (lane & 48) + g * 4 + r, 64);
      #pragma unroll
      for (int df = 0; df < 4; ++df)
        #pragma unroll
        for (int r = 0; r < 4; ++r) O[df][r] *= fo[r];
    }

    // ---- two 64-j halves: P -> px (wave-private) -> PV ----
    float psum = 0.f;
    #pragma unroll
    for (int hf = 0; hf < 2; ++hf) {
      #pragma unroll
      for (int j4 = 0; j4 < 4; ++j4) {
        int jf = hf * 4 + j4;
        float p0 = __builtin_amdgcn_exp2f(s[jf][0] - m);
        float p1 = __builtin_amdgcn_exp2f(s[jf][1] - m);
        float p2 = __builtin_amdgcn_exp2f(s[jf][2] - m);
        float p3 = __builtin_amdgcn_exp2f(s[jf][3] - m);
        psum += (p0 + p1) + (p2 + p3);
        ushort4 pk;
        pk.x = f2bfn(p0); pk.y = f2bfn(p1); pk.z = f2bfn(p2); pk.w = f2bfn(p3);
        *(ushort4*)&px[wv][colc][4 * ((j4 * 4 + g) ^ sx)] = pk;
      }
      s8v Pf[2];
      #pragma unroll
      for (int ks = 0; ks < 2; ++ks)
        Pf[ks] = *(const s8v*)&px[wv][colc][4 * ((ks * 8 + 2 * g) ^ sx)];
      __builtin_amdgcn_s_setprio(1);
      #pragma unroll
      for (int df = 0; df < 4; ++df) {
        const char* vp = Vb + (df * 16 + colc) * 256;
        #pragma unroll
        for (int ks = 0; ks < 2; ++ks) {
          s8v Vf = *(const s8v*)(vp + ((hf * 128 + ks * 64 + g * 16) ^ swv));
          O[df] = mfma16(Pf[ks], Vf, O[df]);
        }
      }
      __builtin_amdgcn_s_setprio(0);
    }
    psum += __shfl_xor(psum, 16, 64);
    psum += __shfl_xor(psum, 32, 64);
    lsum += psum;
  };

  STAGE(jt_lo, KsmA, VsmA);
  int jt = jt_lo;
  while (true) {
    if (jt + 1 <= jt_hi) { STAGE(jt + 1, KsmB, VsmB); WAIT_VMCNT(4); }
    else                 { WAIT_VMCNT(0); }
    SBAR();
    COMPUTE(jt << 7, (const char*)KsmA, (const char*)VsmA);
    SBAR();
    if (++jt > jt_hi) break;
    if (jt + 1 <= jt_hi) { STAGE(jt + 1, KsmA, VsmA); WAIT_VMCNT(4); }
    else                 { WAIT_VMCNT(0); }
    SBAR();
    COMPUTE(jt << 7, (const char*)KsmB, (const char*)VsmB);
    SBAR();
    if (++jt > jt_hi) break;
  }

  // ---- epilogue ----
  float linv[4];
  #pragma unroll
  for (int r = 0; r < 4; ++r)
    linv[r] = 1.0f / __shfl(lsum, (lane & 48) + g * 4 + r, 64);
  #pragma unroll
  for (int df = 0; df < 4; ++df) {
    #pragma unroll
    for (int r = 0; r < 4; ++r) {
      int i = q0 + g * 4 + r;
      ao[((size_t)b * 1024 + i) * 1024 + h * 64 + df * 16 + colc] =
          f2bfn(O[df][r] * linv[r]);
    }
  }
}

// ---------------------------------------------------------------------------
// attn_sparse: top-k regime fallback (cold at runtime).
// ---------------------------------------------------------------------------
__global__ __launch_bounds__(256) void attn_sparse(
    const unsigned short* __restrict__ qx, const unsigned short* __restrict__ kx,
    const unsigned short* __restrict__ vx, const int* __restrict__ meta,
    unsigned short* __restrict__ ao) {
  __shared__ float S[32][1028];
  __shared__ float qs[32][68];
  __shared__ float kc[64][68];
  __shared__ float rowsum_s[32];

  int tid = threadIdx.x;
  int lane = tid & 63;
  int wv = tid >> 6;
  int id = blockIdx.x;
  int rt = id & 31;
  int h = (id >> 5) & 15;
  int b = id >> 9;
  int bh = b * 16 + h;
  int row0 = rt * 32;

  const int* mb = meta + b * 8;
  int t00 = mb[0], t10 = mb[1], t01 = mb[2], t11 = mb[3], needs = mb[4];
  if (!needs) return;

  #pragma unroll
  for (int i = 0; i < 8; ++i) {
    int idx = tid + 256 * i;
    int r = idx >> 6, d = idx & 63;
    qs[r][d] = bf2f(qx[((size_t)bh * 1024 + row0 + r) * 64 + d]);
  }

  int lr = lane >> 4, lc = lane & 15;
  int r_a = wv * 8 + lr * 2;
  int r_b = r_a + 1;

  for (int cb = 0; cb < 16; ++cb) {
    __syncthreads();
    #pragma unroll
    for (int i = 0; i < 2; ++i) {
      int idx = tid + 256 * i;
      int cc = idx >> 3, d0 = (idx & 7) * 8;
      union { s8v v; unsigned short u[8]; } kv8;
      kv8.v = *(const s8v*)(kx + ((size_t)bh * 1024 + cb * 64 + cc) * 64 + d0);
      #pragma unroll
      for (int j = 0; j < 8; ++j) kc[cc][d0 + j] = bf2f(kv8.u[j]);
    }
    __syncthreads();

    float acc0[4] = {0.f, 0.f, 0.f, 0.f};
    float acc1[4] = {0.f, 0.f, 0.f, 0.f};
    for (int dq = 0; dq < 64; dq += 4) {
      float4 qa = *(const float4*)&qs[r_a][dq];
      float4 qb = *(const float4*)&qs[r_b][dq];
      #pragma unroll
      for (int cj = 0; cj < 4; ++cj) {
        float4 kv = *(const float4*)&kc[lc + 16 * cj][dq];
        acc0[cj] += qa.x * kv.x + qa.y * kv.y + qa.z * kv.z + qa.w * kv.w;
        acc1[cj] += qb.x * kv.x + qb.y * kv.y + qb.z * kv.z + qb.w * kv.w;
      }
    }
    #pragma unroll
    for (int cj = 0; cj < 4; ++cj) {
      S[r_a][cb * 64 + lc + 16 * cj] = acc0[cj] * LN2_;
      S[r_b][cb * 64 + lc + 16 * cj] = acc1[cj] * LN2_;
    }
  }

  for (int rr = 0; rr < 8; ++rr) {
    int r = wv * 8 + rr;
    int grow = row0 + r;
    float sv[16];
    unsigned kv[16];
    #pragma unroll
    for (int i2 = 0; i2 < 16; ++i2) {
      float s = S[r][lane + 64 * i2];
      sv[i2] = s;
      unsigned u = __float_as_uint(s);
      kv[i2] = (u & 0x80000000u) ? ~u : (u | 0x80000000u);
    }
    unsigned T = 0u;
    for (int bit = 31; bit >= 0; --bit) {
      unsigned cand = T | (1u << bit);
      int cnt = 0;
      #pragma unroll
      for (int i2 = 0; i2 < 16; ++i2) cnt += (kv[i2] >= cand) ? 1 : 0;
      for (int off = 32; off; off >>= 1) cnt += __shfl_xor(cnt, off, 64);
      if (cnt >= KTOP_) T = cand;
    }
    float mx = -INFINITY;
    int kept = 0;
    unsigned kmask = 0;
    #pragma unroll
    for (int i2 = 0; i2 < 16; ++i2) {
      int j = lane + 64 * i2;
      int sp = (kv[i2] >= T) ? 1 : 0;
      int dj = grow - j;
      int lo = (dj <= 16 && dj >= -16) ? 1 : 0;
      int keep = sp ? (lo ? t11 : t01) : (lo ? t10 : t00);
      kept += keep;
      if (keep) { kmask |= (1u << i2); mx = fmaxf(mx, sv[i2]); }
    }
    for (int off = 32; off; off >>= 1) {
      mx = fmaxf(mx, __shfl_xor(mx, off, 64));
      kept += __shfl_xor(kept, off, 64);
    }
    if (kept == 0) {
      #pragma unroll
      for (int i2 = 0; i2 < 16; ++i2) {
        int j = lane + 64 * i2;
        S[r][j] = (j == grow) ? 1.0f : 0.0f;
      }
      if (lane == 0) rowsum_s[r] = 1.0f;
    } else {
      float sum = 0.f;
      #pragma unroll
      for (int i2 = 0; i2 < 16; ++i2) {
        float p = ((kmask >> i2) & 1u) ? __expf(sv[i2] - mx) : 0.0f;
        sum += p;
        S[r][lane + 64 * i2] = p;
      }
      for (int off = 32; off; off >>= 1) sum += __shfl_xor(sum, off, 64);
      if (lane == 0) rowsum_s[r] = sum;
    }
  }

  int ld = lane & 15;
  int d0 = ld * 4;
  float4 oa0 = make_float4(0.f, 0.f, 0.f, 0.f);
  float4 oa1 = make_float4(0.f, 0.f, 0.f, 0.f);
  for (int vb = 0; vb < 16; ++vb) {
    __syncthreads();
    #pragma unroll
    for (int i = 0; i < 2; ++i) {
      int idx = tid + 256 * i;
      int d = idx >> 3, c0 = (idx & 7) * 8;
      union { s8v v; unsigned short u[8]; } vv8;
      vv8.v = *(const s8v*)(vx + ((size_t)bh * 64 + d) * 1024 + vb * 64 + c0);
      #pragma unroll
      for (int j = 0; j < 8; ++j) kc[c0 + j][d] = bf2f(vv8.u[j]);
    }
    __syncthreads();
    for (int cq = 0; cq < 64; cq += 4) {
      float4 pa = *(const float4*)&S[r_a][vb * 64 + cq];
      float4 pb = *(const float4*)&S[r_b][vb * 64 + cq];
      float par[4] = {pa.x, pa.y, pa.z, pa.w};
      float pbr[4] = {pb.x, pb.y, pb.z, pb.w};
      #pragma unroll
      for (int tt = 0; tt < 4; ++tt) {
        float4 vv = *(const float4*)&kc[cq + tt][d0];
        oa0.x += par[tt] * vv.x; oa0.y += par[tt] * vv.y;
        oa0.z += par[tt] * vv.z; oa0.w += par[tt] * vv.w;
        oa1.x += pbr[tt] * vv.x; oa1.y += pbr[tt] * vv.y;
        oa1.z += pbr[tt] * vv.z; oa1.w += pbr[tt] * vv.w;
      }
    }
  }
  float inv0 = 1.0f / rowsum_s[r_a];
  float inv1 = 1.0f / rowsum_s[r_b];
  ushort4 o0, o1;
  unsigned short* o0p = (unsigned short*)&o0;
  unsigned short* o1p = (unsigned short*)&o1;
  float v0[4] = {oa0.x * inv0, oa0.y * inv0, oa0.z * inv0, oa0.w * inv0};
  float v1[4] = {oa1.x * inv1, oa1.y * inv1, oa1.z * inv1, oa1.w * inv1};
  #pragma unroll
  for (int j = 0; j < 4; ++j) {
    o0p[j] = f2bf(v0[j]);
    o1p[j] = f2bf(v1[j]);
  }
  *(ushort4*)(ao + ((size_t)b * 1024 + row0 + r_a) * 1024 + h * 64 + d0) = o0;
  *(ushort4*)(ao + ((size_t)b * 1024 + row0 + r_b) * 1024 + h * 64 + d0) = o1;
}

// ---------------------------------------------------------------------------
// Fallback f32 kernels (small-ws force path only)
// ---------------------------------------------------------------------------
__global__ __launch_bounds__(256) void pool_kernel(const float* __restrict__ x,
                                                   float* __restrict__ pooled) {
  int g = blockIdx.x * 256 + threadIdx.x;
  int b = g >> 10, d = g & 1023;
  const float* xp = x + ((size_t)b << 20) + d;
  float s = 0.f, m = -INFINITY;
  #pragma unroll 4
  for (int l = 0; l < 1024; ++l) {
    float v = xp[(size_t)l << 10];
    s += v;
    m = fmaxf(m, v);
  }
  pooled[g] = (s * (1.0f / 1024.0f) + m) * 0.5f;
}

__global__ __launch_bounds__(256) void qkv_gemm(const float* __restrict__ X,
                                                const float* __restrict__ W,
                                                float* __restrict__ qw,
                                                float* __restrict__ kw,
                                                float* __restrict__ vw) {
  __shared__ float As[8][128];
  __shared__ float Bs[8][128];
  int tid = threadIdx.x;
  int row0 = blockIdx.y * 128, col0 = blockIdx.x * 128;
  int lr = tid >> 1;
  int lk = (tid & 1) * 4;
  int ty = tid >> 4, tx = tid & 15;
  float acc[8][8] = {};

  for (int kb = 0; kb < 1024; kb += 8) {
    float4 a4 = *(const float4*)(X + (size_t)(row0 + lr) * 1024 + kb + lk);
    float4 b4 = *(const float4*)(W + (size_t)(col0 + lr) * 1024 + kb + lk);
    __syncthreads();
    As[lk + 0][lr] = a4.x; As[lk + 1][lr] = a4.y; As[lk + 2][lr] = a4.z; As[lk + 3][lr] = a4.w;
    Bs[lk + 0][lr] = b4.x; Bs[lk + 1][lr] = b4.y; Bs[lk + 2][lr] = b4.z; Bs[lk + 3][lr] = b4.w;
    __syncthreads();
    #pragma unroll
    for (int kk = 0; kk < 8; ++kk) {
      float av[8], bv[8];
      #pragma unroll
      for (int i = 0; i < 8; ++i) av[i] = As[kk][ty * 8 + i];
      #pragma unroll
      for (int j = 0; j < 8; ++j) bv[j] = Bs[kk][tx * 8 + j];
      #pragma unroll
      for (int i = 0; i < 8; ++i)
        #pragma unroll
        for (int j = 0; j < 8; ++j) acc[i][j] += av[i] * bv[j];
    }
  }
  #pragma unroll
  for (int i = 0; i < 8; ++i) {
    int m = row0 + ty * 8 + i;
    int bb = m >> 10, l = m & 1023;
    #pragma unroll
    for (int j = 0; j < 8; j += 4) {
      int n = col0 + tx * 8 + j;
      int c = n >> 10;
      int hh = (n >> 6) & 15;
      int hd = n & 63;
      float* base = (c == 0) ? qw : (c == 1) ? kw : vw;
      float* dst = base + ((size_t)(bb * 16 + hh) * 1024 + l) * 64 + hd;
      *(float4*)dst = make_float4(acc[i][j], acc[i][j + 1], acc[i][j + 2], acc[i][j + 3]);
    }
  }
}

__global__ __launch_bounds__(256) void proj_gemm(const float* __restrict__ A,
                                                 const float* __restrict__ W,
                                                 const float* __restrict__ bias,
                                                 float* __restrict__ out) {
  __shared__ float As[8][128];
  __shared__ float Bs[8][128];
  int tid = threadIdx.x;
  int row0 = blockIdx.y * 128, col0 = blockIdx.x * 128;
  int lr = tid >> 1;
  int lk = (tid & 1) * 4;
  int ty = tid >> 4, tx = tid & 15;
  float acc[8][8] = {};

  for (int kb = 0; kb < 1024; kb += 8) {
    float4 a4 = *(const float4*)(A + (size_t)(row0 + lr) * 1024 + kb + lk);
    float4 b4 = *(const float4*)(W + (size_t)(col0 + lr) * 1024 + kb + lk);
    __syncthreads();
    As[lk + 0][lr] = a4.x; As[lk + 1][lr] = a4.y; As[lk + 2][lr] = a4.z; As[lk + 3][lr] = a4.w;
    Bs[lk + 0][lr] = b4.x; Bs[lk + 1][lr] = b4.y; Bs[lk + 2][lr] = b4.z; Bs[lk + 3][lr] = b4.w;
    __syncthreads();
    #pragma unroll
    for (int kk = 0; kk < 8; ++kk) {
      float av[8], bv[8];
      #pragma unroll
      for (int i = 0; i < 8; ++i) av[i] = As[kk][ty * 8 + i];
      #pragma unroll
      for (int j = 0; j < 8; ++j) bv[j] = Bs[kk][tx * 8 + j];
      #pragma unroll
      for (int i = 0; i < 8; ++i)
        #pragma unroll
        for (int j = 0; j < 8; ++j) acc[i][j] += av[i] * bv[j];
    }
  }
  #pragma unroll
  for (int i = 0; i < 8; ++i) {
    int m = row0 + ty * 8 + i;
    #pragma unroll
    for (int j = 0; j < 8; j += 4) {
      int n = col0 + tx * 8 + j;
      *(float4*)(out + (size_t)m * 1024 + n) =
          make_float4(acc[i][j] + bias[n], acc[i][j + 1] + bias[n + 1],
                      acc[i][j + 2] + bias[n + 2], acc[i][j + 3] + bias[n + 3]);
    }
  }
}

__global__ __launch_bounds__(256) void pattern_kernel(
    const float* __restrict__ pooled,
    const float* __restrict__ w1, const float* __restrict__ b1,
    const float* __restrict__ lng, const float* __restrict__ lnb,
    const float* __restrict__ w2, const float* __restrict__ b2,
    const float* __restrict__ w3, const float* __restrict__ b3,
    const float* __restrict__ pb, int* __restrict__ meta) {
  __shared__ float pool_s[1024];
  __shared__ float h1[1024];
  __shared__ float h2[512];
  __shared__ float red[256];
  int b = blockIdx.x, t = threadIdx.x;

  for (int i = t; i < 1024; i += 256) pool_s[i] = pooled[b * 1024 + i];
  __syncthreads();
  for (int o = t; o < 1024; o += 256) {
    float acc = b1[o];
    const float* wr = w1 + (size_t)o * 1024;
    for (int k = 0; k < 1024; ++k) acc += pool_s[k] * wr[k];
    h1[o] = acc;
  }
  __syncthreads();
  float ls = 0.f;
  for (int i = t; i < 1024; i += 256) ls += h1[i];
  red[t] = ls; __syncthreads();
  for (int s = 128; s > 0; s >>= 1) { if (t < s) red[t] += red[t + s]; __syncthreads(); }
  float mean = red[0] * (1.0f / 1024.0f);
  __syncthreads();
  float lq = 0.f;
  for (int i = t; i < 1024; i += 256) { float dv = h1[i] - mean; lq += dv * dv; }
  red[t] = lq; __syncthreads();
  for (int s = 128; s > 0; s >>= 1) { if (t < s) red[t] += red[t + s]; __syncthreads(); }
  float var = red[0] * (1.0f / 1024.0f);
  float rstd = 1.0f / sqrtf(var + 1e-5f);
  __syncthreads();
  for (int i = t; i < 1024; i += 256) {
    float v = (h1[i] - mean) * rstd * lng[i] + lnb[i];
    h1[i] = 0.5f * v * (1.0f + erff(v * 0.70710678118654752f));
  }
  __syncthreads();
  for (int o = t; o < 512; o += 256) {
    float acc = b2[o];
    const float* wr = w2 + (size_t)o * 1024;
    for (int k = 0; k < 1024; ++k) acc += h1[k] * wr[k];
    h2[o] = 0.5f * acc * (1.0f + erff(acc * 0.70710678118654752f));
  }
  __syncthreads();
  float lgv[3];
  for (int c = 0; c < 3; ++c) {
    float p = 0.f;
    for (int i = t; i < 512; i += 256) p += h2[i] * w3[c * 512 + i];
    __syncthreads();
    red[t] = p; __syncthreads();
    for (int s = 128; s > 0; s >>= 1) { if (t < s) red[t] += red[t + s]; __syncthreads(); }
    lgv[c] = red[0] + b3[c] + pb[c];
  }
  if (t == 0) {
    float mx = fmaxf(lgv[0], fmaxf(lgv[1], lgv[2]));
    float e0 = __expf(lgv[0] - mx), e1 = __expf(lgv[1] - mx), e2 = __expf(lgv[2] - mx);
    float inv = 1.0f / (e0 + e1 + e2);
    float p0 = e0 * inv, p1 = e1 * inv, p2 = e2 * inv;
    float c00 = p1;
    float c10 = p0 + p1;
    float c01 = p1 + p2;
    float c11 = (p0 + p1) + p2;
    int t00 = c00 > 0.1f, t10 = c10 > 0.1f, t01 = c01 > 0.1f, t11 = c11 > 0.1f;
    meta[b * 8 + 0] = t00;
    meta[b * 8 + 1] = t10;
    meta[b * 8 + 2] = t01;
    meta[b * 8 + 3] = t11;
    meta[b * 8 + 4] = (t00 != t01) || (t10 != t11);
  }
}

__global__ __launch_bounds__(256) void attn_kernel_f32(const float* __restrict__ qw,
                                                       const float* __restrict__ kw,
                                                       const float* __restrict__ vw,
                                                       const int* __restrict__ meta,
                                                       float* __restrict__ ao) {
  __shared__ float S[32][1028];
  __shared__ float qs[32][68];
  __shared__ float kc[64][68];
  __shared__ float rowsum_s[32];

  int tid = threadIdx.x;
  int lane = tid & 63;
  int wv = tid >> 6;
  int id = blockIdx.x;
  int rt = id & 31;
  int h = (id >> 5) & 15;
  int b = id >> 9;
  int bh = b * 16 + h;
  int row0 = rt * 32;

  const int* mb = meta + b * 8;
  int t00 = mb[0], t10 = mb[1], t01 = mb[2], t11 = mb[3], needs = mb[4];

  {
    const float4* qp = (const float4*)(qw + ((size_t)bh * 1024 + row0 + wv * 8) * 64);
    #pragma unroll
    for (int i = 0; i < 2; ++i) {
      int f = lane + 64 * i;
      float4 v = qp[f];
      int r = wv * 8 + (f >> 4);
      int d = (f & 15) << 2;
      qs[r][d] = v.x; qs[r][d + 1] = v.y; qs[r][d + 2] = v.z; qs[r][d + 3] = v.w;
    }
  }

  int lr = lane >> 4, lc = lane & 15;
  int r_a = wv * 8 + lr * 2;
  int r_b = r_a + 1;

  for (int cb = 0; cb < 16; ++cb) {
    __syncthreads();
    const float4* kp = (const float4*)(kw + ((size_t)bh * 1024 + cb * 64) * 64);
    #pragma unroll
    for (int i = 0; i < 4; ++i) {
      int f = tid + 256 * i;
      float4 v = kp[f];
      int c = f >> 4, d = (f & 15) << 2;
      kc[c][d] = v.x; kc[c][d + 1] = v.y; kc[c][d + 2] = v.z; kc[c][d + 3] = v.w;
    }
    __syncthreads();

    float acc0[4] = {0.f, 0.f, 0.f, 0.f};
    float acc1[4] = {0.f, 0.f, 0.f, 0.f};
    for (int dq = 0; dq < 64; dq += 4) {
      float4 qa = *(const float4*)&qs[r_a][dq];
      float4 qb = *(const float4*)&qs[r_b][dq];
      #pragma unroll
      for (int cj = 0; cj < 4; ++cj) {
        float4 kv = *(const float4*)&kc[lc + 16 * cj][dq];
        acc0[cj] += qa.x * kv.x + qa.y * kv.y + qa.z * kv.z + qa.w * kv.w;
        acc1[cj] += qb.x * kv.x + qb.y * kv.y + qb.z * kv.z + qb.w * kv.w;
      }
    }
    #pragma unroll
    for (int cj = 0; cj < 4; ++cj) {
      S[r_a][cb * 64 + lc + 16 * cj] = acc0[cj] * SCALE_;
      S[r_b][cb * 64 + lc + 16 * cj] = acc1[cj] * SCALE_;
    }
  }

  for (int rr = 0; rr < 8; ++rr) {
    int r = wv * 8 + rr;
    int grow = row0 + r;
    float sv[16];
    unsigned kv[16];
    #pragma unroll
    for (int i2 = 0; i2 < 16; ++i2) {
      float s = S[r][lane + 64 * i2];
      sv[i2] = s;
      unsigned u = __float_as_uint(s);
      kv[i2] = (u & 0x80000000u) ? ~u : (u | 0x80000000u);
    }
    unsigned T = 0u;
    if (needs) {
      for (int bit = 31; bit >= 0; --bit) {
        unsigned cand = T | (1u << bit);
        int cnt = 0;
        #pragma unroll
        for (int i2 = 0; i2 < 16; ++i2) cnt += (kv[i2] >= cand) ? 1 : 0;
        for (int off = 32; off; off >>= 1) cnt += __shfl_xor(cnt, off, 64);
        if (cnt >= KTOP_) T = cand;
      }
    }
    float mx = -INFINITY;
    int kept = 0;
    unsigned kmask = 0;
    #pragma unroll
    for (int i2 = 0; i2 < 16; ++i2) {
      int j = lane + 64 * i2;
      int sp = (kv[i2] >= T) ? 1 : 0;
      int dj = grow - j;
      int lo = (dj <= 16 && dj >= -16) ? 1 : 0;
      int keep = sp ? (lo ? t11 : t01) : (lo ? t10 : t00);
      kept += keep;
      if (keep) { kmask |= (1u << i2); mx = fmaxf(mx, sv[i2]); }
    }
    for (int off = 32; off; off >>= 1) {
      mx = fmaxf(mx, __shfl_xor(mx, off, 64));
      kept += __shfl_xor(kept, off, 64);
    }
    if (kept == 0) {
      #pragma unroll
      for (int i2 = 0; i2 < 16; ++i2) {
        int j = lane + 64 * i2;
        S[r][j] = (j == grow) ? 1.0f : 0.0f;
      }
      if (lane == 0) rowsum_s[r] = 1.0f;
    } else {
      float sum = 0.f;
      #pragma unroll
      for (int i2 = 0; i2 < 16; ++i2) {
        float p = ((kmask >> i2) & 1u) ? __expf(sv[i2] - mx) : 0.0f;
        sum += p;
        S[r][lane + 64 * i2] = p;
      }
      for (int off = 32; off; off >>= 1) sum += __shfl_xor(sum, off, 64);
      if (lane == 0) rowsum_s[r] = sum;
    }
  }

  int ld = lane & 15;
  int d0 = ld * 4;
  float4 oa0 = make_float4(0.f, 0.f, 0.f, 0.f);
  float4 oa1 = make_float4(0.f, 0.f, 0.f, 0.f);
  for (int vb = 0; vb < 16; ++vb) {
    __syncthreads();
    const float4* vp = (const float4*)(vw + ((size_t)bh * 1024 + vb * 64) * 64);
    #pragma unroll
    for (int i = 0; i < 4; ++i) {
      int f = tid + 256 * i;
      float4 v = vp[f];
      int c = f >> 4, d = (f & 15) << 2;
      kc[c][d] = v.x; kc[c][d + 1] = v.y; kc[c][d + 2] = v.z; kc[c][d + 3] = v.w;
    }
    __syncthreads();
    for (int cq = 0; cq < 64; cq += 4) {
      float4 pa = *(const float4*)&S[r_a][vb * 64 + cq];
      float4 pb = *(const float4*)&S[r_b][vb * 64 + cq];
      float par[4] = {pa.x, pa.y, pa.z, pa.w};
      float pbr[4] = {pb.x, pb.y, pb.z, pb.w};
      #pragma unroll
      for (int tt = 0; tt < 4; ++tt) {
        float4 vv = *(const float4*)&kc[cq + tt][d0];
        oa0.x += par[tt] * vv.x; oa0.y += par[tt] * vv.y;
        oa0.z += par[tt] * vv.z; oa0.w += par[tt] * vv.w;
        oa1.x += pbr[tt] * vv.x; oa1.y += pbr[tt] * vv.y;
        oa1.z += pbr[tt] * vv.z; oa1.w += pbr[tt] * vv.w;
      }
    }
  }
  float inv0 = 1.0f / rowsum_s[r_a];
  float inv1 = 1.0f / rowsum_s[r_b];
  float* p0 = ao + ((size_t)b * 1024 + row0 + r_a) * 1024 + h * 64 + d0;
  float* p1 = ao + ((size_t)b * 1024 + row0 + r_b) * 1024 + h * 64 + d0;
  *(float4*)p0 = make_float4(oa0.x * inv0, oa0.y * inv0, oa0.z * inv0, oa0.w * inv0);
  *(float4*)p1 = make_float4(oa1.x * inv1, oa1.y * inv1, oa1.z * inv1, oa1.w * inv1);
}

// ---------------------------------------------------------------------------
extern "C" void kernel_launch(void* const* d_in, const int* in_sizes, int n_in,
                              void* d_out, int out_size, void* d_ws, size_t ws_size,
                              hipStream_t stream) {
  const float* x      = (const float*)d_in[0];
  const float* w_qkv  = (const float*)d_in[1];
  const float* w_proj = (const float*)d_in[2];
  const float* b_proj = (const float*)d_in[3];
  const float* ps_w1  = (const float*)d_in[4];
  const float* ps_b1  = (const float*)d_in[5];
  const float* ln_g   = (const float*)d_in[6];
  const float* ln_b   = (const float*)d_in[7];
  const float* ps_w2  = (const float*)d_in[8];
  const float* ps_b2  = (const float*)d_in[9];
  const float* ps_w3  = (const float*)d_in[10];
  const float* ps_b3  = (const float*)d_in[11];
  const float* pbias  = (const float*)d_in[12];
  // d_in[13]=sparse_w, d_in[14]=sparse_b: monotone per-row affine -> top-k invariant.

  float* ws = (float*)d_ws;
  float* pooled = ws;                              // 4096 (force path)
  int*   meta   = (int*)(ws + 4096);               // 32
  float* h1buf  = ws + 8192;                       // 4096
  float* h2buf  = ws + 12288;                      // 2048
  float* ppsum  = ws + 16384;                      // 262144
  float* ppmax  = ws + 278528;                     // 262144
  float* qw = ws + 1048576;                        // 4M each (force path)
  float* kw = qw + 4194304;
  float* vw = kw + 4194304;
  float* ao = vw + 4194304;
  unsigned short* u16b = (unsigned short*)(ao + 4194304);
  unsigned short* xs   = u16b;                     // [4096][1024]   4.19M u16
  unsigned short* wqs  = xs + 4194304;             // [3072][1024]   3.15M
  unsigned short* wps  = wqs + 3145728;            // [1024][1024]   1.05M
  unsigned short* aos  = wps + 1048576;            // [4096][1024]   4.19M
  unsigned short* qx   = aos + 4194304;            // [64][1024][64] 4.19M
  unsigned short* kx   = qx + 4194304;             // 4.19M
  unsigned short* vx   = kx + 4194304;             // [64][64][1024] 4.19M
  float* out = (float*)d_out;

  const size_t NEED_FULL = (size_t)(1048576 + 4 * 4194304) * 4 +
                           (size_t)(4194304 + 3145728 + 1048576 + 4194304 +
                                    3 * 4194304) * 2;

  if (ws_size >= NEED_FULL) {
    pool1<<<256, 256, 0, stream>>>(x, ppsum, ppmax, xs);
    ps_gemv1<<<64, 256, 0, stream>>>(ppsum, ppmax, ps_w1, ps_b1, h1buf);
    ps_gemv2<<<32, 256, 0, stream>>>(h1buf, ln_g, ln_b, ps_w2, ps_b2, h2buf);
    ps_logits<<<4, 256, 0, stream>>>(h2buf, ps_w3, ps_b3, pbias, meta);

    prep_w<<<4096, 256, 0, stream>>>(w_qkv, w_proj, wqs, wps);
    gemm_sp<0, 128, 192><<<512, 256, 0, stream>>>(xs, wqs, nullptr, qx, kx, vx,
                                                  nullptr, 16);

    attn_flash<<<512, 512, 0, stream>>>(qx, kx, vx, meta, aos);
    attn_sparse<<<2048, 256, 0, stream>>>(qx, kx, vx, meta, aos);

    gemm_sp<1, 64, 128><<<512, 256, 0, stream>>>(aos, wps, b_proj,
                                                 nullptr, nullptr, nullptr, out, 8);
  } else {
    // fallback: f32 path (needs only the f32 region)
    pool_kernel<<<16, 256, 0, stream>>>(x, pooled);
    pattern_kernel<<<4, 256, 0, stream>>>(pooled, ps_w1, ps_b1, ln_g, ln_b,
                                          ps_w2, ps_b2, ps_w3, ps_b3, pbias, meta);
    qkv_gemm<<<dim3(24, 32), 256, 0, stream>>>(x, w_qkv, qw, kw, vw);
    attn_kernel_f32<<<2048, 256, 0, stream>>>(qw, kw, vw, meta, ao);
    proj_gemm<<<dim3(8, 32), 256, 0, stream>>>(ao, w_proj, b_proj, out);
  }
}

// Round 15
// 134.556 us; speedup vs baseline: 1.0572x; 1.0572x over previous
//
#include <hip/hip_runtime.h>
#include <math.h>

// Problem constants
#define KTOP_ 716
#define SCALE_ 0.125f
#define QSCALE_ 0.1803368801111731f   // 0.125 * log2(e): softmax in exp2 domain
#define LN2_ 0.6931471805599453f

#define WAIT_VMCNT(n) asm volatile("s_waitcnt vmcnt(" #n ")" ::: "memory")
static __device__ inline void SBAR() {
  __builtin_amdgcn_sched_barrier(0);
  __builtin_amdgcn_s_barrier();
  __builtin_amdgcn_sched_barrier(0);
}

typedef float f4v __attribute__((ext_vector_type(4)));
typedef short s8v __attribute__((ext_vector_type(8)));
typedef __bf16 bf8v __attribute__((ext_vector_type(8)));

static __device__ inline unsigned short f2bf(float f) {
  unsigned u = __float_as_uint(f);
  u += 0x7fffu + ((u >> 16) & 1u);
  return (unsigned short)(u >> 16);
}
static __device__ inline unsigned short f2bfn(float f) {
  union { __bf16 b; unsigned short u; } cv;
  cv.b = (__bf16)f;           // compiler emits v_cvt_pk_bf16_f32 for pairs
  return cv.u;
}
static __device__ inline float bf2f(unsigned short h) {
  return __uint_as_float((unsigned)h << 16);
}
static __device__ inline f4v mfma16(s8v a, s8v b, f4v c) {
  union { s8v s; bf8v b; } ua, ub;
  ua.s = a; ub.s = b;
  return __builtin_amdgcn_mfma_f32_16x16x32_bf16(ua.b, ub.b, c, 0, 0, 0);
}
static __device__ inline void gload16(const unsigned short* g, unsigned short* lbase) {
  __builtin_amdgcn_global_load_lds(
      (const __attribute__((address_space(1))) unsigned int*)g,
      (__attribute__((address_space(3))) unsigned int*)lbase, 16, 0, 0);
}

// ---------------------------------------------------------------------------
// pool1 (fused: also emits xs = bf16 of x); partial sums/maxes to ppsum/ppmax
// ---------------------------------------------------------------------------
__global__ __launch_bounds__(256) void pool1(const float* __restrict__ x,
                                             float* __restrict__ psum,
                                             float* __restrict__ pmax,
                                             unsigned short* __restrict__ xs) {
  int bid = blockIdx.x;            // b*64 + sl
  int b = bid >> 6, sl = bid & 63;
  int t = threadIdx.x;
  float s[4] = {0.f, 0.f, 0.f, 0.f};
  float m[4] = {-INFINITY, -INFINITY, -INFINITY, -INFINITY};
  const float* xb = x + ((size_t)b << 20) + (size_t)sl * 16 * 1024;
  unsigned short* xo = xs + ((size_t)(b * 1024 + sl * 16)) * 1024;
  for (int l = 0; l < 16; ++l) {
    #pragma unroll
    for (int dg = 0; dg < 4; ++dg) {
      float v = xb[l * 1024 + dg * 256 + t];
      s[dg] += v;
      m[dg] = fmaxf(m[dg], v);
      xo[(size_t)l * 1024 + dg * 256 + t] = f2bfn(v);
    }
  }
  #pragma unroll
  for (int dg = 0; dg < 4; ++dg) {
    psum[(size_t)bid * 1024 + dg * 256 + t] = s[dg];
    pmax[(size_t)bid * 1024 + dg * 256 + t] = m[dg];
  }
}

// ---------------------------------------------------------------------------
// ps_gemv1 (fused pool2)
// ---------------------------------------------------------------------------
__global__ __launch_bounds__(256) void ps_gemv1(const float* __restrict__ psum,
                                                const float* __restrict__ pmax,
                                                const float* __restrict__ w1,
                                                const float* __restrict__ b1,
                                                float* __restrict__ h1) {
  __shared__ float pool_s[1024];
  int bid = blockIdx.x;            // b*16 + og
  int b = bid >> 4, og = bid & 15;
  int t = threadIdx.x;
  #pragma unroll
  for (int i = 0; i < 4; ++i) {
    int d = t + 256 * i;
    float s = 0.f, m = -INFINITY;
    #pragma unroll 8
    for (int sl = 0; sl < 64; ++sl) {
      s += psum[((size_t)b * 64 + sl) * 1024 + d];
      m = fmaxf(m, pmax[((size_t)b * 64 + sl) * 1024 + d]);
    }
    pool_s[d] = (s * (1.0f / 1024.0f) + m) * 0.5f;
  }
  __syncthreads();
  int ol = t >> 2, ks = t & 3;
  int o = og * 64 + ol;
  const float4* wr = (const float4*)(w1 + (size_t)o * 1024 + ks * 256);
  const float4* pp = (const float4*)(&pool_s[ks * 256]);
  float acc = 0.f;
  #pragma unroll 8
  for (int j = 0; j < 64; ++j) {
    float4 a = wr[j], p = pp[j];
    acc += a.x * p.x + a.y * p.y + a.z * p.z + a.w * p.w;
  }
  acc += __shfl_xor(acc, 1, 64);
  acc += __shfl_xor(acc, 2, 64);
  if (ks == 0) h1[b * 1024 + o] = acc + b1[o];
}

// ---------------------------------------------------------------------------
// ps_gemv2 (fused LN)
// ---------------------------------------------------------------------------
__global__ __launch_bounds__(256) void ps_gemv2(const float* __restrict__ h1,
                                                const float* __restrict__ lng,
                                                const float* __restrict__ lnb,
                                                const float* __restrict__ w2,
                                                const float* __restrict__ b2,
                                                float* __restrict__ h2) {
  __shared__ float hs[1024];
  __shared__ float red[256];
  int bid = blockIdx.x;            // b*8 + og
  int b = bid >> 3, og = bid & 7;
  int t = threadIdx.x;
  const float* hb = h1 + b * 1024;
  float v0[4];
  float ls = 0.f;
  #pragma unroll
  for (int i = 0; i < 4; ++i) { v0[i] = hb[t + 256 * i]; ls += v0[i]; }
  red[t] = ls; __syncthreads();
  for (int s = 128; s > 0; s >>= 1) { if (t < s) red[t] += red[t + s]; __syncthreads(); }
  float mean = red[0] * (1.0f / 1024.0f);
  __syncthreads();
  float lq = 0.f;
  #pragma unroll
  for (int i = 0; i < 4; ++i) { float dv = v0[i] - mean; lq += dv * dv; }
  red[t] = lq; __syncthreads();
  for (int s = 128; s > 0; s >>= 1) { if (t < s) red[t] += red[t + s]; __syncthreads(); }
  float rstd = 1.0f / sqrtf(red[0] * (1.0f / 1024.0f) + 1e-5f);
  #pragma unroll
  for (int i = 0; i < 4; ++i) {
    float v = (v0[i] - mean) * rstd * lng[t + 256 * i] + lnb[t + 256 * i];
    hs[t + 256 * i] = 0.5f * v * (1.0f + erff(v * 0.70710678118654752f));
  }
  __syncthreads();
  int ol = t >> 2, ks = t & 3;
  int o = og * 64 + ol;
  const float4* wr = (const float4*)(w2 + (size_t)o * 1024 + ks * 256);
  const float4* pp = (const float4*)(&hs[ks * 256]);
  float acc = 0.f;
  #pragma unroll 8
  for (int j = 0; j < 64; ++j) {
    float4 a = wr[j], p = pp[j];
    acc += a.x * p.x + a.y * p.y + a.z * p.z + a.w * p.w;
  }
  acc += __shfl_xor(acc, 1, 64);
  acc += __shfl_xor(acc, 2, 64);
  if (ks == 0) {
    float v = acc + b2[o];
    h2[b * 512 + o] = 0.5f * v * (1.0f + erff(v * 0.70710678118654752f));
  }
}

__global__ __launch_bounds__(256) void ps_logits(const float* __restrict__ h2,
                                                 const float* __restrict__ w3,
                                                 const float* __restrict__ b3,
                                                 const float* __restrict__ pb,
                                                 int* __restrict__ meta) {
  __shared__ float red[256];
  int b = blockIdx.x, t = threadIdx.x;
  float lgv[3];
  for (int c = 0; c < 3; ++c) {
    float p = 0.f;
    for (int i = t; i < 512; i += 256) p += h2[b * 512 + i] * w3[c * 512 + i];
    red[t] = p; __syncthreads();
    for (int s = 128; s > 0; s >>= 1) { if (t < s) red[t] += red[t + s]; __syncthreads(); }
    lgv[c] = red[0] + b3[c] + pb[c];
    __syncthreads();
  }
  if (t == 0) {
    float mx = fmaxf(lgv[0], fmaxf(lgv[1], lgv[2]));
    float e0 = __expf(lgv[0] - mx), e1 = __expf(lgv[1] - mx), e2 = __expf(lgv[2] - mx);
    float inv = 1.0f / (e0 + e1 + e2);
    float p0 = e0 * inv, p1 = e1 * inv, p2 = e2 * inv;
    float c00 = p1;
    float c10 = p0 + p1;
    float c01 = p1 + p2;
    float c11 = (p0 + p1) + p2;
    int t00 = c00 > 0.1f, t10 = c10 > 0.1f, t01 = c01 > 0.1f, t11 = c11 > 0.1f;
    meta[b * 8 + 0] = t00;
    meta[b * 8 + 1] = t10;
    meta[b * 8 + 2] = t01;
    meta[b * 8 + 3] = t11;
    meta[b * 8 + 4] = (t00 != t01) || (t10 != t11);
  }
}

// ---------------------------------------------------------------------------
// prep_w: both weight matrices -> bf16 in one launch
// ---------------------------------------------------------------------------
__global__ __launch_bounds__(256) void prep_w(const float* __restrict__ w_qkv,
                                              const float* __restrict__ w_proj,
                                              unsigned short* __restrict__ wqs,
                                              unsigned short* __restrict__ wps) {
  int i = blockIdx.x * 256 + threadIdx.x;
  const float* src;
  unsigned short* dst;
  int idx;
  if (i < 786432) { src = w_qkv; dst = wqs; idx = i; }
  else            { src = w_proj; dst = wps; idx = i - 786432; }
  float4 v = ((const float4*)src)[idx];
  ushort4 o;
  o.x = f2bfn(v.x); o.y = f2bfn(v.y); o.z = f2bfn(v.z); o.w = f2bfn(v.w);
  *(ushort4*)(dst + (size_t)idx * 4) = o;
}

// ---------------------------------------------------------------------------
// gemm_sp<MODE,TM>: C[M][N] = A[M][1024].B[N][1024] (bf16, K=1024, TN=128)
// counted-vmcnt pipeline (T4), named double buffers, XOR-swizzled LDS.
// MODE 0 (128x128): L2-compact XCD mapping (8 rows x 12 cols/XCD, 8x8 order).
// MODE 1 (64x128): out = C + bias.
// ---------------------------------------------------------------------------
template <int MODE, int TM>
__global__ __launch_bounds__(256) void gemm_sp(
    const unsigned short* __restrict__ A, const unsigned short* __restrict__ B,
    const float* __restrict__ bias,
    unsigned short* __restrict__ qxo, unsigned short* __restrict__ kxo,
    unsigned short* __restrict__ vxo,
    float* __restrict__ out, int Nb) {
  constexpr int MFR = TM / 32;               // 16-row frags per wave (4 or 2)
  __shared__ unsigned short AsmA[TM * 64];
  __shared__ unsigned short AsmB[TM * 64];
  __shared__ unsigned short BsmA[128 * 64];
  __shared__ unsigned short BsmB[128 * 64];

  int bid = blockIdx.x;
  int bm, bn;
  if (MODE == 0) {
    int xcd = bid & 7, idx = bid >> 3;       // idx 0..95
    int rb = (xcd >> 1) * 8, cb = (xcd & 1) * 12;
    int r, c;
    if (idx < 64) { r = idx & 7; c = idx >> 3; }
    else          { int j = idx - 64; r = j & 7; c = 8 + (j >> 3); }
    bm = rb + r; bn = cb + c;
  } else {
    int cpx = gridDim.x >> 3;
    int g = (bid & 7) * cpx + (bid >> 3);
    bm = g / Nb; bn = g % Nb;
  }
  size_t row0 = (size_t)bm * TM, col0 = (size_t)bn * 128;

  int tid = threadIdx.x, lane = tid & 63, wv = tid >> 6;
  int wm = (wv >> 1) * (MFR * 16), wn = (wv & 1) << 6;
  int rowg = lane >> 4, colc = lane & 15;

  f4v acc[MFR][4];
  #pragma unroll
  for (int mf = 0; mf < MFR; ++mf)
    #pragma unroll
    for (int nf = 0; nf < 4; ++nf) acc[mf][nf] = (f4v){0.f, 0.f, 0.f, 0.f};

  const unsigned short* Abase = A + row0 * 1024;
  const unsigned short* Bbase = B + col0 * 1024;

  auto STAGE = [&](int kb, unsigned short* Ad, unsigned short* Bd) {
    #pragma unroll
    for (int p = 0; p < TM / 32; ++p) {
      int idx = p * 256 + tid;
      int row = idx >> 3;
      int sc = (idx & 7) ^ (row & 7);
      gload16(Abase + (size_t)row * 1024 + kb + sc * 8,
              Ad + (size_t)(p * 256 + wv * 64) * 8);
    }
    #pragma unroll
    for (int p = 0; p < 4; ++p) {
      int idx = p * 256 + tid;
      int row = idx >> 3;
      int sc = (idx & 7) ^ (row & 7);
      gload16(Bbase + (size_t)row * 1024 + kb + sc * 8,
              Bd + (size_t)(p * 256 + wv * 64) * 8);
    }
  };

  auto COMPUTE = [&](const unsigned short* Ab, const unsigned short* Bb) {
    #pragma unroll
    for (int ks = 0; ks < 2; ++ks) {
      s8v af[MFR], bf_[4];
      #pragma unroll
      for (int mf = 0; mf < MFR; ++mf) {
        int row = wm + mf * 16 + colc;
        int kby = (ks * 64 + rowg * 16) ^ ((row & 7) << 4);
        af[mf] = *(const s8v*)((const char*)Ab + row * 128 + kby);
      }
      #pragma unroll
      for (int nf = 0; nf < 4; ++nf) {
        int row = wn + nf * 16 + colc;
        int kby = (ks * 64 + rowg * 16) ^ ((row & 7) << 4);
        bf_[nf] = *(const s8v*)((const char*)Bb + row * 128 + kby);
      }
      __builtin_amdgcn_s_setprio(1);
      #pragma unroll
      for (int mf = 0; mf < MFR; ++mf)
        #pragma unroll
        for (int nf = 0; nf < 4; ++nf)
          acc[mf][nf] = mfma16(af[mf], bf_[nf], acc[mf][nf]);
      __builtin_amdgcn_s_setprio(0);
    }
  };

  STAGE(0, AsmA, BsmA);
  for (int kb = 0; kb < 1024; kb += 128) {
    STAGE(kb + 64, AsmB, BsmB);
    if constexpr (TM == 128) WAIT_VMCNT(8); else WAIT_VMCNT(6);
    SBAR();
    COMPUTE(AsmA, BsmA);
    SBAR();
    if (kb + 128 < 1024) {
      STAGE(kb + 128, AsmA, BsmA);
      if constexpr (TM == 128) WAIT_VMCNT(8); else WAIT_VMCNT(6);
    } else {
      WAIT_VMCNT(0);
    }
    SBAR();
    COMPUTE(AsmB, BsmB);
    SBAR();
  }

  if (MODE == 0) {
    int c = (int)(col0 >> 10);   // 0=q 1=k 2=v (tiles never straddle)
    #pragma unroll
    for (int mf = 0; mf < MFR; ++mf) {
      int m0 = (int)row0 + wm + mf * 16 + rowg * 4;
      int bb = m0 >> 10, l0 = m0 & 1023;   // l0 % 4 == 0, 4 consecutive l
      #pragma unroll
      for (int nf = 0; nf < 4; ++nf) {
        int n = (int)col0 + wn + nf * 16 + colc;
        int hh = (n >> 6) & 15, hd = n & 63;
        int bhl = bb * 16 + hh;
        if (c == 2) {
          ushort4 h4;
          h4.x = f2bfn(acc[mf][nf][0]);
          h4.y = f2bfn(acc[mf][nf][1]);
          h4.z = f2bfn(acc[mf][nf][2]);
          h4.w = f2bfn(acc[mf][nf][3]);
          *(ushort4*)(vxo + ((size_t)bhl * 64 + hd) * 1024 + l0) = h4;
        } else {
          unsigned short* dst = ((c == 0) ? qxo : kxo) +
                                ((size_t)bhl * 1024 + l0) * 64 + hd;
          float sc_ = (c == 0) ? QSCALE_ : 1.0f;
          #pragma unroll
          for (int r = 0; r < 4; ++r)
            dst[(size_t)r * 64] = f2bfn(acc[mf][nf][r] * sc_);
        }
      }
    }
  } else {
    #pragma unroll
    for (int mf = 0; mf < MFR; ++mf) {
      #pragma unroll
      for (int r = 0; r < 4; ++r) {
        int m = (int)row0 + wm + mf * 16 + rowg * 4 + r;
        #pragma unroll
        for (int nf = 0; nf < 4; ++nf) {
          int n = (int)col0 + wn + nf * 16 + colc;
          out[(size_t)m * 1024 + n] = acc[mf][nf][r] + bias[n];
        }
      }
    }
  }
}

// ---------------------------------------------------------------------------
// attn_flash v9: KVBLK=128 (8 j-tiles). 512 threads / 8 waves / 128 q-rows;
// counted vmcnt; named buffers; V 16-slot XOR swizzle; px reused per half.
// ---------------------------------------------------------------------------
__global__ __launch_bounds__(512) void attn_flash(
    const unsigned short* __restrict__ qx, const unsigned short* __restrict__ kx,
    const unsigned short* __restrict__ vx, const int* __restrict__ meta,
    unsigned short* __restrict__ ao) {
  int n = blockIdx.x;                    // 512 blocks: 64 bh x 8 qt2
  int bh = ((n & 7) << 3) | (n >> 6);    // XCD swizzle (bijective)
  int qt2 = (n >> 3) & 7;
  int b = bh >> 4, h = bh & 15;
  const int* mb = meta + b * 8;
  if (mb[4]) return;  // sparse regime -> attn_sparse owns this batch
  int t00 = mb[0], t10 = mb[1];

  int tid = threadIdx.x, lane = tid & 63, wv = tid >> 6;
  int g = lane >> 4, colc = lane & 15;
  int bq0 = qt2 * 128;
  int q0 = bq0 + wv * 16;

  if (!t10) {
    // self-only: out row = v row (cold path; vx is transposed [d][l])
    #pragma unroll
    for (int it = 0; it < 4; ++it) {
      int idx = tid + it * 512;
      int r = idx >> 4, dc = (idx & 15) * 4;
      ushort4 o;
      unsigned short* op = (unsigned short*)&o;
      #pragma unroll
      for (int j = 0; j < 4; ++j)
        op[j] = vx[((size_t)bh * 64 + dc + j) * 1024 + bq0 + r];
      *(ushort4*)(ao + ((size_t)b * 1024 + bq0 + r) * 1024 + h * 64 + dc) = o;
    }
    return;
  }
  bool local_only = !t00;

  __shared__ __align__(16) unsigned short KsmA[128 * 64];   // 128 j x 64 d
  __shared__ __align__(16) unsigned short KsmB[128 * 64];
  __shared__ __align__(16) unsigned short VsmA[64 * 128];   // 64 d x 128 j
  __shared__ __align__(16) unsigned short VsmB[64 * 128];
  __shared__ __align__(16) unsigned short px[8][16][64];    // per-wave, reused

  // Q fragments (B operand: row=i=colc, 2 k-steps cover K=64)
  const unsigned short* qb = qx + ((size_t)bh * 1024 + q0 + colc) * 64 + g * 8;
  s8v Q0 = *(const s8v*)(qb);
  s8v Q1 = *(const s8v*)(qb + 32);

  f4v O[4];
  #pragma unroll
  for (int df = 0; df < 4; ++df) O[df] = (f4v){0.f, 0.f, 0.f, 0.f};
  float m = -1e30f, lsum = 0.f;   // per-lane: row i = q0+colc

  const unsigned short* kxb = kx + ((size_t)bh << 10) * 64;
  const unsigned short* vxb = vx + ((size_t)bh << 16);

  int jt_lo = 0, jt_hi = 7;
  if (local_only) {
    int lo = (bq0 - 16) >> 7, hi = (bq0 + 143) >> 7;
    jt_lo = lo < 0 ? 0 : lo;
    jt_hi = hi > 7 ? 7 : hi;
  }

  auto STAGE = [&](int jt, unsigned short* Kd, unsigned short* Vd) {
    int jc = jt << 7;
    #pragma unroll
    for (int p = 0; p < 2; ++p) {
      int cidx = p * 512 + tid;
      // K: 128 rows x 128B (8 chunks/row)
      int krow = cidx >> 3;
      int ksc = (cidx & 7) ^ (krow & 7);
      gload16(kxb + (size_t)(jc + krow) * 64 + ksc * 8,
              Kd + (size_t)(p * 512 + wv * 64) * 8);
      // V: 64 d-rows x 256B (16 chunks/row)
      int vrow = cidx >> 4;
      int vsc = (cidx & 15) ^ (vrow & 15);
      gload16(vxb + (size_t)vrow * 1024 + jc + vsc * 8,
              Vd + (size_t)(p * 512 + wv * 64) * 8);
    }
  };

  int swk = (colc & 7) << 4;       // K read swizzle (j-row & 7 == colc & 7)
  int swv = colc << 4;             // V read swizzle (d-row & 15 == colc)
  int sx = (colc & 7) << 1;        // px slot swizzle

  auto COMPUTE = [&](int jc0, const char* Kb, const char* Vb) {
    if (local_only && (jc0 + 127 < q0 - 16 || jc0 > q0 + 31)) return;
    // ---- S^T: s[jf][r] = S[j=jc0+jf*16+4g+r][i=q0+colc], jf=0..7 ----
    f4v s[8];
    __builtin_amdgcn_s_setprio(1);
    #pragma unroll
    for (int jf = 0; jf < 8; ++jf) {
      const char* kp = Kb + (jf * 16 + colc) * 128;
      s8v K0 = *(const s8v*)(kp + ((g * 16) ^ swk));
      s8v K1 = *(const s8v*)(kp + ((64 + g * 16) ^ swk));
      f4v acc = (f4v){0.f, 0.f, 0.f, 0.f};
      acc = mfma16(K0, Q0, acc);
      acc = mfma16(K1, Q1, acc);
      s[jf] = acc;
    }
    __builtin_amdgcn_s_setprio(0);

    if (local_only) {
      int i = q0 + colc;
      #pragma unroll
      for (int jf = 0; jf < 8; ++jf)
        #pragma unroll
        for (int r = 0; r < 4; ++r) {
          int j = jc0 + jf * 16 + 4 * g + r;
          int dj = i - j;
          if (dj > 16 || dj < -16) s[jf][r] = -1e30f;
        }
    }

    // ---- per-row (per-lane) chunk max over 32 values ----
    float cm = -1e30f;
    #pragma unroll
    for (int jf = 0; jf < 8; ++jf)
      #pragma unroll
      for (int r = 0; r < 4; ++r) cm = fmaxf(cm, s[jf][r]);
    cm = fmaxf(cm, __shfl_xor(cm, 16, 64));
    cm = fmaxf(cm, __shfl_xor(cm, 32, 64));

    // T13 defer-rescale
    if (__any(cm > m + 8.0f)) {
      float mn = fmaxf(m, cm);
      float fac = __builtin_amdgcn_exp2f(m - mn);
      m = mn;
      lsum *= fac;
      float fo[4];
      #pragma unroll
      for (int r = 0; r < 4; ++r)
        fo[r] = __shfl(fac, (lane & 48) + g * 4 + r, 64);
      #pragma unroll
      for (int df = 0; df < 4; ++df)
        #pragma unroll
        for (int r = 0; r < 4; ++r) O[df][r] *= fo[r];
    }

    // ---- two 64-j halves: P -> px (wave-private) -> PV ----
    float psum = 0.f;
    #pragma unroll
    for (int hf = 0; hf < 2; ++hf) {
      #pragma unroll
      for (int j4 = 0; j4 < 4; ++j4) {
        int jf = hf * 4 + j4;
        float p0 = __builtin_amdgcn_exp2f(s[jf][0] - m);
        float p1 = __builtin_amdgcn_exp2f(s[jf][1] - m);
        float p2 = __builtin_amdgcn_exp2f(s[jf][2] - m);
        float p3 = __builtin_amdgcn_exp2f(s[jf][3] - m);
        psum += (p0 + p1) + (p2 + p3);
        ushort4 pk;
        pk.x = f2bfn(p0); pk.y = f2bfn(p1); pk.z = f2bfn(p2); pk.w = f2bfn(p3);
        *(ushort4*)&px[wv][colc][4 * ((j4 * 4 + g) ^ sx)] = pk;
      }
      s8v Pf[2];
      #pragma unroll
      for (int ks = 0; ks < 2; ++ks)
        Pf[ks] = *(const s8v*)&px[wv][colc][4 * ((ks * 8 + 2 * g) ^ sx)];
      __builtin_amdgcn_s_setprio(1);
      #pragma unroll
      for (int df = 0; df < 4; ++df) {
        const char* vp = Vb + (df * 16 + colc) * 256;
        #pragma unroll
        for (int ks = 0; ks < 2; ++ks) {
          s8v Vf = *(const s8v*)(vp + ((hf * 128 + ks * 64 + g * 16) ^ swv));
          O[df] = mfma16(Pf[ks], Vf, O[df]);
        }
      }
      __builtin_amdgcn_s_setprio(0);
    }
    psum += __shfl_xor(psum, 16, 64);
    psum += __shfl_xor(psum, 32, 64);
    lsum += psum;
  };

  STAGE(jt_lo, KsmA, VsmA);
  int jt = jt_lo;
  while (true) {
    if (jt + 1 <= jt_hi) { STAGE(jt + 1, KsmB, VsmB); WAIT_VMCNT(4); }
    else                 { WAIT_VMCNT(0); }
    SBAR();
    COMPUTE(jt << 7, (const char*)KsmA, (const char*)VsmA);
    SBAR();
    if (++jt > jt_hi) break;
    if (jt + 1 <= jt_hi) { STAGE(jt + 1, KsmA, VsmA); WAIT_VMCNT(4); }
    else                 { WAIT_VMCNT(0); }
    SBAR();
    COMPUTE(jt << 7, (const char*)KsmB, (const char*)VsmB);
    SBAR();
    if (++jt > jt_hi) break;
  }

  // ---- epilogue ----
  float linv[4];
  #pragma unroll
  for (int r = 0; r < 4; ++r)
    linv[r] = 1.0f / __shfl(lsum, (lane & 48) + g * 4 + r, 64);
  #pragma unroll
  for (int df = 0; df < 4; ++df) {
    #pragma unroll
    for (int r = 0; r < 4; ++r) {
      int i = q0 + g * 4 + r;
      ao[((size_t)b * 1024 + i) * 1024 + h * 64 + df * 16 + colc] =
          f2bfn(O[df][r] * linv[r]);
    }
  }
}

// ---------------------------------------------------------------------------
// attn_sparse: top-k regime fallback (cold at runtime).
// ---------------------------------------------------------------------------
__global__ __launch_bounds__(256) void attn_sparse(
    const unsigned short* __restrict__ qx, const unsigned short* __restrict__ kx,
    const unsigned short* __restrict__ vx, const int* __restrict__ meta,
    unsigned short* __restrict__ ao) {
  __shared__ float S[32][1028];
  __shared__ float qs[32][68];
  __shared__ float kc[64][68];
  __shared__ float rowsum_s[32];

  int tid = threadIdx.x;
  int lane = tid & 63;
  int wv = tid >> 6;
  int id = blockIdx.x;
  int rt = id & 31;
  int h = (id >> 5) & 15;
  int b = id >> 9;
  int bh = b * 16 + h;
  int row0 = rt * 32;

  const int* mb = meta + b * 8;
  int t00 = mb[0], t10 = mb[1], t01 = mb[2], t11 = mb[3], needs = mb[4];
  if (!needs) return;

  #pragma unroll
  for (int i = 0; i < 8; ++i) {
    int idx = tid + 256 * i;
    int r = idx >> 6, d = idx & 63;
    qs[r][d] = bf2f(qx[((size_t)bh * 1024 + row0 + r) * 64 + d]);
  }

  int lr = lane >> 4, lc = lane & 15;
  int r_a = wv * 8 + lr * 2;
  int r_b = r_a + 1;

  for (int cb = 0; cb < 16; ++cb) {
    __syncthreads();
    #pragma unroll
    for (int i = 0; i < 2; ++i) {
      int idx = tid + 256 * i;
      int cc = idx >> 3, d0 = (idx & 7) * 8;
      union { s8v v; unsigned short u[8]; } kv8;
      kv8.v = *(const s8v*)(kx + ((size_t)bh * 1024 + cb * 64 + cc) * 64 + d0);
      #pragma unroll
      for (int j = 0; j < 8; ++j) kc[cc][d0 + j] = bf2f(kv8.u[j]);
    }
    __syncthreads();

    float acc0[4] = {0.f, 0.f, 0.f, 0.f};
    float acc1[4] = {0.f, 0.f, 0.f, 0.f};
    for (int dq = 0; dq < 64; dq += 4) {
      float4 qa = *(const float4*)&qs[r_a][dq];
      float4 qb = *(const float4*)&qs[r_b][dq];
      #pragma unroll
      for (int cj = 0; cj < 4; ++cj) {
        float4 kv = *(const float4*)&kc[lc + 16 * cj][dq];
        acc0[cj] += qa.x * kv.x + qa.y * kv.y + qa.z * kv.z + qa.w * kv.w;
        acc1[cj] += qb.x * kv.x + qb.y * kv.y + qb.z * kv.z + qb.w * kv.w;
      }
    }
    #pragma unroll
    for (int cj = 0; cj < 4; ++cj) {
      S[r_a][cb * 64 + lc + 16 * cj] = acc0[cj] * LN2_;
      S[r_b][cb * 64 + lc + 16 * cj] = acc1[cj] * LN2_;
    }
  }

  for (int rr = 0; rr < 8; ++rr) {
    int r = wv * 8 + rr;
    int grow = row0 + r;
    float sv[16];
    unsigned kv[16];
    #pragma unroll
    for (int i2 = 0; i2 < 16; ++i2) {
      float s = S[r][lane + 64 * i2];
      sv[i2] = s;
      unsigned u = __float_as_uint(s);
      kv[i2] = (u & 0x80000000u) ? ~u : (u | 0x80000000u);
    }
    unsigned T = 0u;
    for (int bit = 31; bit >= 0; --bit) {
      unsigned cand = T | (1u << bit);
      int cnt = 0;
      #pragma unroll
      for (int i2 = 0; i2 < 16; ++i2) cnt += (kv[i2] >= cand) ? 1 : 0;
      for (int off = 32; off; off >>= 1) cnt += __shfl_xor(cnt, off, 64);
      if (cnt >= KTOP_) T = cand;
    }
    float mx = -INFINITY;
    int kept = 0;
    unsigned kmask = 0;
    #pragma unroll
    for (int i2 = 0; i2 < 16; ++i2) {
      int j = lane + 64 * i2;
      int sp = (kv[i2] >= T) ? 1 : 0;
      int dj = grow - j;
      int lo = (dj <= 16 && dj >= -16) ? 1 : 0;
      int keep = sp ? (lo ? t11 : t01) : (lo ? t10 : t00);
      kept += keep;
      if (keep) { kmask |= (1u << i2); mx = fmaxf(mx, sv[i2]); }
    }
    for (int off = 32; off; off >>= 1) {
      mx = fmaxf(mx, __shfl_xor(mx, off, 64));
      kept += __shfl_xor(kept, off, 64);
    }
    if (kept == 0) {
      #pragma unroll
      for (int i2 = 0; i2 < 16; ++i2) {
        int j = lane + 64 * i2;
        S[r][j] = (j == grow) ? 1.0f : 0.0f;
      }
      if (lane == 0) rowsum_s[r] = 1.0f;
    } else {
      float sum = 0.f;
      #pragma unroll
      for (int i2 = 0; i2 < 16; ++i2) {
        float p = ((kmask >> i2) & 1u) ? __expf(sv[i2] - mx) : 0.0f;
        sum += p;
        S[r][lane + 64 * i2] = p;
      }
      for (int off = 32; off; off >>= 1) sum += __shfl_xor(sum, off, 64);
      if (lane == 0) rowsum_s[r] = sum;
    }
  }

  int ld = lane & 15;
  int d0 = ld * 4;
  float4 oa0 = make_float4(0.f, 0.f, 0.f, 0.f);
  float4 oa1 = make_float4(0.f, 0.f, 0.f, 0.f);
  for (int vb = 0; vb < 16; ++vb) {
    __syncthreads();
    #pragma unroll
    for (int i = 0; i < 2; ++i) {
      int idx = tid + 256 * i;
      int d = idx >> 3, c0 = (idx & 7) * 8;
      union { s8v v; unsigned short u[8]; } vv8;
      vv8.v = *(const s8v*)(vx + ((size_t)bh * 64 + d) * 1024 + vb * 64 + c0);
      #pragma unroll
      for (int j = 0; j < 8; ++j) kc[c0 + j][d] = bf2f(vv8.u[j]);
    }
    __syncthreads();
    for (int cq = 0; cq < 64; cq += 4) {
      float4 pa = *(const float4*)&S[r_a][vb * 64 + cq];
      float4 pb = *(const float4*)&S[r_b][vb * 64 + cq];
      float par[4] = {pa.x, pa.y, pa.z, pa.w};
      float pbr[4] = {pb.x, pb.y, pb.z, pb.w};
      #pragma unroll
      for (int tt = 0; tt < 4; ++tt) {
        float4 vv = *(const float4*)&kc[cq + tt][d0];
        oa0.x += par[tt] * vv.x; oa0.y += par[tt] * vv.y;
        oa0.z += par[tt] * vv.z; oa0.w += par[tt] * vv.w;
        oa1.x += pbr[tt] * vv.x; oa1.y += pbr[tt] * vv.y;
        oa1.z += pbr[tt] * vv.z; oa1.w += pbr[tt] * vv.w;
      }
    }
  }
  float inv0 = 1.0f / rowsum_s[r_a];
  float inv1 = 1.0f / rowsum_s[r_b];
  ushort4 o0, o1;
  unsigned short* o0p = (unsigned short*)&o0;
  unsigned short* o1p = (unsigned short*)&o1;
  float v0[4] = {oa0.x * inv0, oa0.y * inv0, oa0.z * inv0, oa0.w * inv0};
  float v1[4] = {oa1.x * inv1, oa1.y * inv1, oa1.z * inv1, oa1.w * inv1};
  #pragma unroll
  for (int j = 0; j < 4; ++j) {
    o0p[j] = f2bf(v0[j]);
    o1p[j] = f2bf(v1[j]);
  }
  *(ushort4*)(ao + ((size_t)b * 1024 + row0 + r_a) * 1024 + h * 64 + d0) = o0;
  *(ushort4*)(ao + ((size_t)b * 1024 + row0 + r_b) * 1024 + h * 64 + d0) = o1;
}

// ---------------------------------------------------------------------------
// Fallback f32 kernels (small-ws force path only)
// ---------------------------------------------------------------------------
__global__ __launch_bounds__(256) void pool_kernel(const float* __restrict__ x,
                                                   float* __restrict__ pooled) {
  int g = blockIdx.x * 256 + threadIdx.x;
  int b = g >> 10, d = g & 1023;
  const float* xp = x + ((size_t)b << 20) + d;
  float s = 0.f, m = -INFINITY;
  #pragma unroll 4
  for (int l = 0; l < 1024; ++l) {
    float v = xp[(size_t)l << 10];
    s += v;
    m = fmaxf(m, v);
  }
  pooled[g] = (s * (1.0f / 1024.0f) + m) * 0.5f;
}

__global__ __launch_bounds__(256) void qkv_gemm(const float* __restrict__ X,
                                                const float* __restrict__ W,
                                                float* __restrict__ qw,
                                                float* __restrict__ kw,
                                                float* __restrict__ vw) {
  __shared__ float As[8][128];
  __shared__ float Bs[8][128];
  int tid = threadIdx.x;
  int row0 = blockIdx.y * 128, col0 = blockIdx.x * 128;
  int lr = tid >> 1;
  int lk = (tid & 1) * 4;
  int ty = tid >> 4, tx = tid & 15;
  float acc[8][8] = {};

  for (int kb = 0; kb < 1024; kb += 8) {
    float4 a4 = *(const float4*)(X + (size_t)(row0 + lr) * 1024 + kb + lk);
    float4 b4 = *(const float4*)(W + (size_t)(col0 + lr) * 1024 + kb + lk);
    __syncthreads();
    As[lk + 0][lr] = a4.x; As[lk + 1][lr] = a4.y; As[lk + 2][lr] = a4.z; As[lk + 3][lr] = a4.w;
    Bs[lk + 0][lr] = b4.x; Bs[lk + 1][lr] = b4.y; Bs[lk + 2][lr] = b4.z; Bs[lk + 3][lr] = b4.w;
    __syncthreads();
    #pragma unroll
    for (int kk = 0; kk < 8; ++kk) {
      float av[8], bv[8];
      #pragma unroll
      for (int i = 0; i < 8; ++i) av[i] = As[kk][ty * 8 + i];
      #pragma unroll
      for (int j = 0; j < 8; ++j) bv[j] = Bs[kk][tx * 8 + j];
      #pragma unroll
      for (int i = 0; i < 8; ++i)
        #pragma unroll
        for (int j = 0; j < 8; ++j) acc[i][j] += av[i] * bv[j];
    }
  }
  #pragma unroll
  for (int i = 0; i < 8; ++i) {
    int m = row0 + ty * 8 + i;
    int bb = m >> 10, l = m & 1023;
    #pragma unroll
    for (int j = 0; j < 8; j += 4) {
      int n = col0 + tx * 8 + j;
      int c = n >> 10;
      int hh = (n >> 6) & 15;
      int hd = n & 63;
      float* base = (c == 0) ? qw : (c == 1) ? kw : vw;
      float* dst = base + ((size_t)(bb * 16 + hh) * 1024 + l) * 64 + hd;
      *(float4*)dst = make_float4(acc[i][j], acc[i][j + 1], acc[i][j + 2], acc[i][j + 3]);
    }
  }
}

__global__ __launch_bounds__(256) void proj_gemm(const float* __restrict__ A,
                                                 const float* __restrict__ W,
                                                 const float* __restrict__ bias,
                                                 float* __restrict__ out) {
  __shared__ float As[8][128];
  __shared__ float Bs[8][128];
  int tid = threadIdx.x;
  int row0 = blockIdx.y * 128, col0 = blockIdx.x * 128;
  int lr = tid >> 1;
  int lk = (tid & 1) * 4;
  int ty = tid >> 4, tx = tid & 15;
  float acc[8][8] = {};

  for (int kb = 0; kb < 1024; kb += 8) {
    float4 a4 = *(const float4*)(A + (size_t)(row0 + lr) * 1024 + kb + lk);
    float4 b4 = *(const float4*)(W + (size_t)(col0 + lr) * 1024 + kb + lk);
    __syncthreads();
    As[lk + 0][lr] = a4.x; As[lk + 1][lr] = a4.y; As[lk + 2][lr] = a4.z; As[lk + 3][lr] = a4.w;
    Bs[lk + 0][lr] = b4.x; Bs[lk + 1][lr] = b4.y; Bs[lk + 2][lr] = b4.z; Bs[lk + 3][lr] = b4.w;
    __syncthreads();
    #pragma unroll
    for (int kk = 0; kk < 8; ++kk) {
      float av[8], bv[8];
      #pragma unroll
      for (int i = 0; i < 8; ++i) av[i] = As[kk][ty * 8 + i];
      #pragma unroll
      for (int j = 0; j < 8; ++j) bv[j] = Bs[kk][tx * 8 + j];
      #pragma unroll
      for (int i = 0; i < 8; ++i)
        #pragma unroll
        for (int j = 0; j < 8; ++j) acc[i][j] += av[i] * bv[j];
    }
  }
  #pragma unroll
  for (int i = 0; i < 8; ++i) {
    int m = row0 + ty * 8 + i;
    #pragma unroll
    for (int j = 0; j < 8; j += 4) {
      int n = col0 + tx * 8 + j;
      *(float4*)(out + (size_t)m * 1024 + n) =
          make_float4(acc[i][j] + bias[n], acc[i][j + 1] + bias[n + 1],
                      acc[i][j + 2] + bias[n + 2], acc[i][j + 3] + bias[n + 3]);
    }
  }
}

__global__ __launch_bounds__(256) void pattern_kernel(
    const float* __restrict__ pooled,
    const float* __restrict__ w1, const float* __restrict__ b1,
    const float* __restrict__ lng, const float* __restrict__ lnb,
    const float* __restrict__ w2, const float* __restrict__ b2,
    const float* __restrict__ w3, const float* __restrict__ b3,
    const float* __restrict__ pb, int* __restrict__ meta) {
  __shared__ float pool_s[1024];
  __shared__ float h1[1024];
  __shared__ float h2[512];
  __shared__ float red[256];
  int b = blockIdx.x, t = threadIdx.x;

  for (int i = t; i < 1024; i += 256) pool_s[i] = pooled[b * 1024 + i];
  __syncthreads();
  for (int o = t; o < 1024; o += 256) {
    float acc = b1[o];
    const float* wr = w1 + (size_t)o * 1024;
    for (int k = 0; k < 1024; ++k) acc += pool_s[k] * wr[k];
    h1[o] = acc;
  }
  __syncthreads();
  float ls = 0.f;
  for (int i = t; i < 1024; i += 256) ls += h1[i];
  red[t] = ls; __syncthreads();
  for (int s = 128; s > 0; s >>= 1) { if (t < s) red[t] += red[t + s]; __syncthreads(); }
  float mean = red[0] * (1.0f / 1024.0f);
  __syncthreads();
  float lq = 0.f;
  for (int i = t; i < 1024; i += 256) { float dv = h1[i] - mean; lq += dv * dv; }
  red[t] = lq; __syncthreads();
  for (int s = 128; s > 0; s >>= 1) { if (t < s) red[t] += red[t + s]; __syncthreads(); }
  float var = red[0] * (1.0f / 1024.0f);
  float rstd = 1.0f / sqrtf(var + 1e-5f);
  __syncthreads();
  for (int i = t; i < 1024; i += 256) {
    float v = (h1[i] - mean) * rstd * lng[i] + lnb[i];
    h1[i] = 0.5f * v * (1.0f + erff(v * 0.70710678118654752f));
  }
  __syncthreads();
  for (int o = t; o < 512; o += 256) {
    float acc = b2[o];
    const float* wr = w2 + (size_t)o * 1024;
    for (int k = 0; k < 1024; ++k) acc += h1[k] * wr[k];
    h2[o] = 0.5f * acc * (1.0f + erff(acc * 0.70710678118654752f));
  }
  __syncthreads();
  float lgv[3];
  for (int c = 0; c < 3; ++c) {
    float p = 0.f;
    for (int i = t; i < 512; i += 256) p += h2[i] * w3[c * 512 + i];
    __syncthreads();
    red[t] = p; __syncthreads();
    for (int s = 128; s > 0; s >>= 1) { if (t < s) red[t] += red[t + s]; __syncthreads(); }
    lgv[c] = red[0] + b3[c] + pb[c];
  }
  if (t == 0) {
    float mx = fmaxf(lgv[0], fmaxf(lgv[1], lgv[2]));
    float e0 = __expf(lgv[0] - mx), e1 = __expf(lgv[1] - mx), e2 = __expf(lgv[2] - mx);
    float inv = 1.0f / (e0 + e1 + e2);
    float p0 = e0 * inv, p1 = e1 * inv, p2 = e2 * inv;
    float c00 = p1;
    float c10 = p0 + p1;
    float c01 = p1 + p2;
    float c11 = (p0 + p1) + p2;
    int t00 = c00 > 0.1f, t10 = c10 > 0.1f, t01 = c01 > 0.1f, t11 = c11 > 0.1f;
    meta[b * 8 + 0] = t00;
    meta[b * 8 + 1] = t10;
    meta[b * 8 + 2] = t01;
    meta[b * 8 + 3] = t11;
    meta[b * 8 + 4] = (t00 != t01) || (t10 != t11);
  }
}

__global__ __launch_bounds__(256) void attn_kernel_f32(const float* __restrict__ qw,
                                                       const float* __restrict__ kw,
                                                       const float* __restrict__ vw,
                                                       const int* __restrict__ meta,
                                                       float* __restrict__ ao) {
  __shared__ float S[32][1028];
  __shared__ float qs[32][68];
  __shared__ float kc[64][68];
  __shared__ float rowsum_s[32];

  int tid = threadIdx.x;
  int lane = tid & 63;
  int wv = tid >> 6;
  int id = blockIdx.x;
  int rt = id & 31;
  int h = (id >> 5) & 15;
  int b = id >> 9;
  int bh = b * 16 + h;
  int row0 = rt * 32;

  const int* mb = meta + b * 8;
  int t00 = mb[0], t10 = mb[1], t01 = mb[2], t11 = mb[3], needs = mb[4];

  {
    const float4* qp = (const float4*)(qw + ((size_t)bh * 1024 + row0 + wv * 8) * 64);
    #pragma unroll
    for (int i = 0; i < 2; ++i) {
      int f = lane + 64 * i;
      float4 v = qp[f];
      int r = wv * 8 + (f >> 4);
      int d = (f & 15) << 2;
      qs[r][d] = v.x; qs[r][d + 1] = v.y; qs[r][d + 2] = v.z; qs[r][d + 3] = v.w;
    }
  }

  int lr = lane >> 4, lc = lane & 15;
  int r_a = wv * 8 + lr * 2;
  int r_b = r_a + 1;

  for (int cb = 0; cb < 16; ++cb) {
    __syncthreads();
    const float4* kp = (const float4*)(kw + ((size_t)bh * 1024 + cb * 64) * 64);
    #pragma unroll
    for (int i = 0; i < 4; ++i) {
      int f = tid + 256 * i;
      float4 v = kp[f];
      int c = f >> 4, d = (f & 15) << 2;
      kc[c][d] = v.x; kc[c][d + 1] = v.y; kc[c][d + 2] = v.z; kc[c][d + 3] = v.w;
    }
    __syncthreads();

    float acc0[4] = {0.f, 0.f, 0.f, 0.f};
    float acc1[4] = {0.f, 0.f, 0.f, 0.f};
    for (int dq = 0; dq < 64; dq += 4) {
      float4 qa = *(const float4*)&qs[r_a][dq];
      float4 qb = *(const float4*)&qs[r_b][dq];
      #pragma unroll
      for (int cj = 0; cj < 4; ++cj) {
        float4 kv = *(const float4*)&kc[lc + 16 * cj][dq];
        acc0[cj] += qa.x * kv.x + qa.y * kv.y + qa.z * kv.z + qa.w * kv.w;
        acc1[cj] += qb.x * kv.x + qb.y * kv.y + qb.z * kv.z + qb.w * kv.w;
      }
    }
    #pragma unroll
    for (int cj = 0; cj < 4; ++cj) {
      S[r_a][cb * 64 + lc + 16 * cj] = acc0[cj] * SCALE_;
      S[r_b][cb * 64 + lc + 16 * cj] = acc1[cj] * SCALE_;
    }
  }

  for (int rr = 0; rr < 8; ++rr) {
    int r = wv * 8 + rr;
    int grow = row0 + r;
    float sv[16];
    unsigned kv[16];
    #pragma unroll
    for (int i2 = 0; i2 < 16; ++i2) {
      float s = S[r][lane + 64 * i2];
      sv[i2] = s;
      unsigned u = __float_as_uint(s);
      kv[i2] = (u & 0x80000000u) ? ~u : (u | 0x80000000u);
    }
    unsigned T = 0u;
    if (needs) {
      for (int bit = 31; bit >= 0; --bit) {
        unsigned cand = T | (1u << bit);
        int cnt = 0;
        #pragma unroll
        for (int i2 = 0; i2 < 16; ++i2) cnt += (kv[i2] >= cand) ? 1 : 0;
        for (int off = 32; off; off >>= 1) cnt += __shfl_xor(cnt, off, 64);
        if (cnt >= KTOP_) T = cand;
      }
    }
    float mx = -INFINITY;
    int kept = 0;
    unsigned kmask = 0;
    #pragma unroll
    for (int i2 = 0; i2 < 16; ++i2) {
      int j = lane + 64 * i2;
      int sp = (kv[i2] >= T) ? 1 : 0;
      int dj = grow - j;
      int lo = (dj <= 16 && dj >= -16) ? 1 : 0;
      int keep = sp ? (lo ? t11 : t01) : (lo ? t10 : t00);
      kept += keep;
      if (keep) { kmask |= (1u << i2); mx = fmaxf(mx, sv[i2]); }
    }
    for (int off = 32; off; off >>= 1) {
      mx = fmaxf(mx, __shfl_xor(mx, off, 64));
      kept += __shfl_xor(kept, off, 64);
    }
    if (kept == 0) {
      #pragma unroll
      for (int i2 = 0; i2 < 16; ++i2) {
        int j = lane + 64 * i2;
        S[r][j] = (j == grow) ? 1.0f : 0.0f;
      }
      if (lane == 0) rowsum_s[r] = 1.0f;
    } else {
      float sum = 0.f;
      #pragma unroll
      for (int i2 = 0; i2 < 16; ++i2) {
        float p = ((kmask >> i2) & 1u) ? __expf(sv[i2] - mx) : 0.0f;
        sum += p;
        S[r][lane + 64 * i2] = p;
      }
      for (int off = 32; off; off >>= 1) sum += __shfl_xor(sum, off, 64);
      if (lane == 0) rowsum_s[r] = sum;
    }
  }

  int ld = lane & 15;
  int d0 = ld * 4;
  float4 oa0 = make_float4(0.f, 0.f, 0.f, 0.f);
  float4 oa1 = make_float4(0.f, 0.f, 0.f, 0.f);
  for (int vb = 0; vb < 16; ++vb) {
    __syncthreads();
    const float4* vp = (const float4*)(vw + ((size_t)bh * 1024 + vb * 64) * 64);
    #pragma unroll
    for (int i = 0; i < 4; ++i) {
      int f = tid + 256 * i;
      float4 v = vp[f];
      int c = f >> 4, d = (f & 15) << 2;
      kc[c][d] = v.x; kc[c][d + 1] = v.y; kc[c][d + 2] = v.z; kc[c][d + 3] = v.w;
    }
    __syncthreads();
    for (int cq = 0; cq < 64; cq += 4) {
      float4 pa = *(const float4*)&S[r_a][vb * 64 + cq];
      float4 pb = *(const float4*)&S[r_b][vb * 64 + cq];
      float par[4] = {pa.x, pa.y, pa.z, pa.w};
      float pbr[4] = {pb.x, pb.y, pb.z, pb.w};
      #pragma unroll
      for (int tt = 0; tt < 4; ++tt) {
        float4 vv = *(const float4*)&kc[cq + tt][d0];
        oa0.x += par[tt] * vv.x; oa0.y += par[tt] * vv.y;
        oa0.z += par[tt] * vv.z; oa0.w += par[tt] * vv.w;
        oa1.x += pbr[tt] * vv.x; oa1.y += pbr[tt] * vv.y;
        oa1.z += pbr[tt] * vv.z; oa1.w += pbr[tt] * vv.w;
      }
    }
  }
  float inv0 = 1.0f / rowsum_s[r_a];
  float inv1 = 1.0f / rowsum_s[r_b];
  float* p0 = ao + ((size_t)b * 1024 + row0 + r_a) * 1024 + h * 64 + d0;
  float* p1 = ao + ((size_t)b * 1024 + row0 + r_b) * 1024 + h * 64 + d0;
  *(float4*)p0 = make_float4(oa0.x * inv0, oa0.y * inv0, oa0.z * inv0, oa0.w * inv0);
  *(float4*)p1 = make_float4(oa1.x * inv1, oa1.y * inv1, oa1.z * inv1, oa1.w * inv1);
}

// ---------------------------------------------------------------------------
extern "C" void kernel_launch(void* const* d_in, const int* in_sizes, int n_in,
                              void* d_out, int out_size, void* d_ws, size_t ws_size,
                              hipStream_t stream) {
  const float* x      = (const float*)d_in[0];
  const float* w_qkv  = (const float*)d_in[1];
  const float* w_proj = (const float*)d_in[2];
  const float* b_proj = (const float*)d_in[3];
  const float* ps_w1  = (const float*)d_in[4];
  const float* ps_b1  = (const float*)d_in[5];
  const float* ln_g   = (const float*)d_in[6];
  const float* ln_b   = (const float*)d_in[7];
  const float* ps_w2  = (const float*)d_in[8];
  const float* ps_b2  = (const float*)d_in[9];
  const float* ps_w3  = (const float*)d_in[10];
  const float* ps_b3  = (const float*)d_in[11];
  const float* pbias  = (const float*)d_in[12];
  // d_in[13]=sparse_w, d_in[14]=sparse_b: monotone per-row affine -> top-k invariant.

  float* ws = (float*)d_ws;
  float* pooled = ws;                              // 4096 (force path)
  int*   meta   = (int*)(ws + 4096);               // 32
  float* h1buf  = ws + 8192;                       // 4096
  float* h2buf  = ws + 12288;                      // 2048
  float* ppsum  = ws + 16384;                      // 262144
  float* ppmax  = ws + 278528;                     // 262144
  float* qw = ws + 1048576;                        // 4M each (force path)
  float* kw = qw + 4194304;
  float* vw = kw + 4194304;
  float* ao = vw + 4194304;
  unsigned short* u16b = (unsigned short*)(ao + 4194304);
  unsigned short* xs   = u16b;                     // [4096][1024]   4.19M u16
  unsigned short* wqs  = xs + 4194304;             // [3072][1024]   3.15M
  unsigned short* wps  = wqs + 3145728;            // [1024][1024]   1.05M
  unsigned short* aos  = wps + 1048576;            // [4096][1024]   4.19M
  unsigned short* qx   = aos + 4194304;            // [64][1024][64] 4.19M
  unsigned short* kx   = qx + 4194304;             // 4.19M
  unsigned short* vx   = kx + 4194304;             // [64][64][1024] 4.19M
  float* out = (float*)d_out;

  const size_t NEED_FULL = (size_t)(1048576 + 4 * 4194304) * 4 +
                           (size_t)(4194304 + 3145728 + 1048576 + 4194304 +
                                    3 * 4194304) * 2;

  if (ws_size >= NEED_FULL) {
    pool1<<<256, 256, 0, stream>>>(x, ppsum, ppmax, xs);
    ps_gemv1<<<64, 256, 0, stream>>>(ppsum, ppmax, ps_w1, ps_b1, h1buf);
    ps_gemv2<<<32, 256, 0, stream>>>(h1buf, ln_g, ln_b, ps_w2, ps_b2, h2buf);
    ps_logits<<<4, 256, 0, stream>>>(h2buf, ps_w3, ps_b3, pbias, meta);

    prep_w<<<4096, 256, 0, stream>>>(w_qkv, w_proj, wqs, wps);
    gemm_sp<0, 128><<<768, 256, 0, stream>>>(xs, wqs, nullptr, qx, kx, vx,
                                             nullptr, 24);

    attn_flash<<<512, 512, 0, stream>>>(qx, kx, vx, meta, aos);
    attn_sparse<<<2048, 256, 0, stream>>>(qx, kx, vx, meta, aos);

    gemm_sp<1, 64><<<512, 256, 0, stream>>>(aos, wps, b_proj,
                                            nullptr, nullptr, nullptr, out, 8);
  } else {
    // fallback: f32 path (needs only the f32 region)
    pool_kernel<<<16, 256, 0, stream>>>(x, pooled);
    pattern_kernel<<<4, 256, 0, stream>>>(pooled, ps_w1, ps_b1, ln_g, ln_b,
                                          ps_w2, ps_b2, ps_w3, ps_b3, pbias, meta);
    qkv_gemm<<<dim3(24, 32), 256, 0, stream>>>(x, w_qkv, qw, kw, vw);
    attn_kernel_f32<<<2048, 256, 0, stream>>>(qw, kw, vw, meta, ao);
    proj_gemm<<<dim3(8, 32), 256, 0, stream>>>(ao, w_proj, b_proj, out);
  }
}

// Round 16
// 133.411 us; speedup vs baseline: 1.0663x; 1.0086x over previous
//
#include <hip/hip_runtime.h>
#include <math.h>

// Problem constants
#define KTOP_ 716
#define SCALE_ 0.125f
#define QSCALE_ 0.1803368801111731f   // 0.125 * log2(e): softmax in exp2 domain
#define LN2_ 0.6931471805599453f

#define WAIT_VMCNT(n) asm volatile("s_waitcnt vmcnt(" #n ")" ::: "memory")
static __device__ inline void SBAR() {
  __builtin_amdgcn_sched_barrier(0);
  __builtin_amdgcn_s_barrier();
  __builtin_amdgcn_sched_barrier(0);
}

typedef float f4v __attribute__((ext_vector_type(4)));
typedef short s8v __attribute__((ext_vector_type(8)));
typedef __bf16 bf8v __attribute__((ext_vector_type(8)));

static __device__ inline unsigned short f2bf(float f) {
  unsigned u = __float_as_uint(f);
  u += 0x7fffu + ((u >> 16) & 1u);
  return (unsigned short)(u >> 16);
}
static __device__ inline unsigned short f2bfn(float f) {
  union { __bf16 b; unsigned short u; } cv;
  cv.b = (__bf16)f;           // compiler emits v_cvt_pk_bf16_f32 for pairs
  return cv.u;
}
static __device__ inline float bf2f(unsigned short h) {
  return __uint_as_float((unsigned)h << 16);
}
static __device__ inline f4v mfma16(s8v a, s8v b, f4v c) {
  union { s8v s; bf8v b; } ua, ub;
  ua.s = a; ub.s = b;
  return __builtin_amdgcn_mfma_f32_16x16x32_bf16(ua.b, ub.b, c, 0, 0, 0);
}
static __device__ inline void gload16(const unsigned short* g, unsigned short* lbase) {
  __builtin_amdgcn_global_load_lds(
      (const __attribute__((address_space(1))) unsigned int*)g,
      (__attribute__((address_space(3))) unsigned int*)lbase, 16, 0, 0);
}

// ---------------------------------------------------------------------------
// pool1 (fused: xs = bf16 of x, AND weight bf16 conversion in extra blocks)
// blocks 0..255: pooling partials + xs. blocks 256..4351: prep wqs/wps.
// ---------------------------------------------------------------------------
__global__ __launch_bounds__(256) void pool1(const float* __restrict__ x,
                                             float* __restrict__ psum,
                                             float* __restrict__ pmax,
                                             unsigned short* __restrict__ xs,
                                             const float* __restrict__ w_qkv,
                                             const float* __restrict__ w_proj,
                                             unsigned short* __restrict__ wqs,
                                             unsigned short* __restrict__ wps) {
  int bid = blockIdx.x;
  int t = threadIdx.x;
  if (bid >= 256) {
    // weight conversion: 4096 blocks x 256 threads x 1 float4
    int i = (bid - 256) * 256 + t;   // 0 .. 1048575
    const float* src;
    unsigned short* dst;
    int idx;
    if (i < 786432) { src = w_qkv; dst = wqs; idx = i; }
    else            { src = w_proj; dst = wps; idx = i - 786432; }
    float4 v = ((const float4*)src)[idx];
    ushort4 o;
    o.x = f2bfn(v.x); o.y = f2bfn(v.y); o.z = f2bfn(v.z); o.w = f2bfn(v.w);
    *(ushort4*)(dst + (size_t)idx * 4) = o;
    return;
  }
  int b = bid >> 6, sl = bid & 63;
  float s[4] = {0.f, 0.f, 0.f, 0.f};
  float m[4] = {-INFINITY, -INFINITY, -INFINITY, -INFINITY};
  const float* xb = x + ((size_t)b << 20) + (size_t)sl * 16 * 1024;
  unsigned short* xo = xs + ((size_t)(b * 1024 + sl * 16)) * 1024;
  for (int l = 0; l < 16; ++l) {
    #pragma unroll
    for (int dg = 0; dg < 4; ++dg) {
      float v = xb[l * 1024 + dg * 256 + t];
      s[dg] += v;
      m[dg] = fmaxf(m[dg], v);
      xo[(size_t)l * 1024 + dg * 256 + t] = f2bfn(v);
    }
  }
  #pragma unroll
  for (int dg = 0; dg < 4; ++dg) {
    psum[(size_t)bid * 1024 + dg * 256 + t] = s[dg];
    pmax[(size_t)bid * 1024 + dg * 256 + t] = m[dg];
  }
}

// ---------------------------------------------------------------------------
// ps_gemv1 (fused pool2)
// ---------------------------------------------------------------------------
__global__ __launch_bounds__(256) void ps_gemv1(const float* __restrict__ psum,
                                                const float* __restrict__ pmax,
                                                const float* __restrict__ w1,
                                                const float* __restrict__ b1,
                                                float* __restrict__ h1) {
  __shared__ float pool_s[1024];
  int bid = blockIdx.x;            // b*16 + og
  int b = bid >> 4, og = bid & 15;
  int t = threadIdx.x;
  #pragma unroll
  for (int i = 0; i < 4; ++i) {
    int d = t + 256 * i;
    float s = 0.f, m = -INFINITY;
    #pragma unroll 8
    for (int sl = 0; sl < 64; ++sl) {
      s += psum[((size_t)b * 64 + sl) * 1024 + d];
      m = fmaxf(m, pmax[((size_t)b * 64 + sl) * 1024 + d]);
    }
    pool_s[d] = (s * (1.0f / 1024.0f) + m) * 0.5f;
  }
  __syncthreads();
  int ol = t >> 2, ks = t & 3;
  int o = og * 64 + ol;
  const float4* wr = (const float4*)(w1 + (size_t)o * 1024 + ks * 256);
  const float4* pp = (const float4*)(&pool_s[ks * 256]);
  float acc = 0.f;
  #pragma unroll 8
  for (int j = 0; j < 64; ++j) {
    float4 a = wr[j], p = pp[j];
    acc += a.x * p.x + a.y * p.y + a.z * p.z + a.w * p.w;
  }
  acc += __shfl_xor(acc, 1, 64);
  acc += __shfl_xor(acc, 2, 64);
  if (ks == 0) h1[b * 1024 + o] = acc + b1[o];
}

// ---------------------------------------------------------------------------
// ps_gemv2 (fused LN)
// ---------------------------------------------------------------------------
__global__ __launch_bounds__(256) void ps_gemv2(const float* __restrict__ h1,
                                                const float* __restrict__ lng,
                                                const float* __restrict__ lnb,
                                                const float* __restrict__ w2,
                                                const float* __restrict__ b2,
                                                float* __restrict__ h2) {
  __shared__ float hs[1024];
  __shared__ float red[256];
  int bid = blockIdx.x;            // b*8 + og
  int b = bid >> 3, og = bid & 7;
  int t = threadIdx.x;
  const float* hb = h1 + b * 1024;
  float v0[4];
  float ls = 0.f;
  #pragma unroll
  for (int i = 0; i < 4; ++i) { v0[i] = hb[t + 256 * i]; ls += v0[i]; }
  red[t] = ls; __syncthreads();
  for (int s = 128; s > 0; s >>= 1) { if (t < s) red[t] += red[t + s]; __syncthreads(); }
  float mean = red[0] * (1.0f / 1024.0f);
  __syncthreads();
  float lq = 0.f;
  #pragma unroll
  for (int i = 0; i < 4; ++i) { float dv = v0[i] - mean; lq += dv * dv; }
  red[t] = lq; __syncthreads();
  for (int s = 128; s > 0; s >>= 1) { if (t < s) red[t] += red[t + s]; __syncthreads(); }
  float rstd = 1.0f / sqrtf(red[0] * (1.0f / 1024.0f) + 1e-5f);
  #pragma unroll
  for (int i = 0; i < 4; ++i) {
    float v = (v0[i] - mean) * rstd * lng[t + 256 * i] + lnb[t + 256 * i];
    hs[t + 256 * i] = 0.5f * v * (1.0f + erff(v * 0.70710678118654752f));
  }
  __syncthreads();
  int ol = t >> 2, ks = t & 3;
  int o = og * 64 + ol;
  const float4* wr = (const float4*)(w2 + (size_t)o * 1024 + ks * 256);
  const float4* pp = (const float4*)(&hs[ks * 256]);
  float acc = 0.f;
  #pragma unroll 8
  for (int j = 0; j < 64; ++j) {
    float4 a = wr[j], p = pp[j];
    acc += a.x * p.x + a.y * p.y + a.z * p.z + a.w * p.w;
  }
  acc += __shfl_xor(acc, 1, 64);
  acc += __shfl_xor(acc, 2, 64);
  if (ks == 0) {
    float v = acc + b2[o];
    h2[b * 512 + o] = 0.5f * v * (1.0f + erff(v * 0.70710678118654752f));
  }
}

__global__ __launch_bounds__(256) void ps_logits(const float* __restrict__ h2,
                                                 const float* __restrict__ w3,
                                                 const float* __restrict__ b3,
                                                 const float* __restrict__ pb,
                                                 int* __restrict__ meta) {
  __shared__ float red[256];
  int b = blockIdx.x, t = threadIdx.x;
  float lgv[3];
  for (int c = 0; c < 3; ++c) {
    float p = 0.f;
    for (int i = t; i < 512; i += 256) p += h2[b * 512 + i] * w3[c * 512 + i];
    red[t] = p; __syncthreads();
    for (int s = 128; s > 0; s >>= 1) { if (t < s) red[t] += red[t + s]; __syncthreads(); }
    lgv[c] = red[0] + b3[c] + pb[c];
    __syncthreads();
  }
  if (t == 0) {
    float mx = fmaxf(lgv[0], fmaxf(lgv[1], lgv[2]));
    float e0 = __expf(lgv[0] - mx), e1 = __expf(lgv[1] - mx), e2 = __expf(lgv[2] - mx);
    float inv = 1.0f / (e0 + e1 + e2);
    float p0 = e0 * inv, p1 = e1 * inv, p2 = e2 * inv;
    float c00 = p1;
    float c10 = p0 + p1;
    float c01 = p1 + p2;
    float c11 = (p0 + p1) + p2;
    int t00 = c00 > 0.1f, t10 = c10 > 0.1f, t01 = c01 > 0.1f, t11 = c11 > 0.1f;
    meta[b * 8 + 0] = t00;
    meta[b * 8 + 1] = t10;
    meta[b * 8 + 2] = t01;
    meta[b * 8 + 3] = t11;
    meta[b * 8 + 4] = (t00 != t01) || (t10 != t11);
  }
}

// ---------------------------------------------------------------------------
// gemm_sp<MODE,TM>: C[M][N] = A[M][1024].B[N][1024] (bf16, K=1024, TN=128)
// counted-vmcnt pipeline (T4), named double buffers, XOR-swizzled LDS.
// MODE 0 (128x128): L2-compact XCD mapping (8 rows x 12 cols/XCD, 8x8 order).
// MODE 1 (64x128): out = C + bias.
// ---------------------------------------------------------------------------
template <int MODE, int TM>
__global__ __launch_bounds__(256) void gemm_sp(
    const unsigned short* __restrict__ A, const unsigned short* __restrict__ B,
    const float* __restrict__ bias,
    unsigned short* __restrict__ qxo, unsigned short* __restrict__ kxo,
    unsigned short* __restrict__ vxo,
    float* __restrict__ out, int Nb) {
  constexpr int MFR = TM / 32;               // 16-row frags per wave (4 or 2)
  __shared__ unsigned short AsmA[TM * 64];
  __shared__ unsigned short AsmB[TM * 64];
  __shared__ unsigned short BsmA[128 * 64];
  __shared__ unsigned short BsmB[128 * 64];

  int bid = blockIdx.x;
  int bm, bn;
  if (MODE == 0) {
    int xcd = bid & 7, idx = bid >> 3;       // idx 0..95
    int rb = (xcd >> 1) * 8, cb = (xcd & 1) * 12;
    int r, c;
    if (idx < 64) { r = idx & 7; c = idx >> 3; }
    else          { int j = idx - 64; r = j & 7; c = 8 + (j >> 3); }
    bm = rb + r; bn = cb + c;
  } else {
    int cpx = gridDim.x >> 3;
    int g = (bid & 7) * cpx + (bid >> 3);
    bm = g / Nb; bn = g % Nb;
  }
  size_t row0 = (size_t)bm * TM, col0 = (size_t)bn * 128;

  int tid = threadIdx.x, lane = tid & 63, wv = tid >> 6;
  int wm = (wv >> 1) * (MFR * 16), wn = (wv & 1) << 6;
  int rowg = lane >> 4, colc = lane & 15;

  f4v acc[MFR][4];
  #pragma unroll
  for (int mf = 0; mf < MFR; ++mf)
    #pragma unroll
    for (int nf = 0; nf < 4; ++nf) acc[mf][nf] = (f4v){0.f, 0.f, 0.f, 0.f};

  const unsigned short* Abase = A + row0 * 1024;
  const unsigned short* Bbase = B + col0 * 1024;

  auto STAGE = [&](int kb, unsigned short* Ad, unsigned short* Bd) {
    #pragma unroll
    for (int p = 0; p < TM / 32; ++p) {
      int idx = p * 256 + tid;
      int row = idx >> 3;
      int sc = (idx & 7) ^ (row & 7);
      gload16(Abase + (size_t)row * 1024 + kb + sc * 8,
              Ad + (size_t)(p * 256 + wv * 64) * 8);
    }
    #pragma unroll
    for (int p = 0; p < 4; ++p) {
      int idx = p * 256 + tid;
      int row = idx >> 3;
      int sc = (idx & 7) ^ (row & 7);
      gload16(Bbase + (size_t)row * 1024 + kb + sc * 8,
              Bd + (size_t)(p * 256 + wv * 64) * 8);
    }
  };

  auto COMPUTE = [&](const unsigned short* Ab, const unsigned short* Bb) {
    #pragma unroll
    for (int ks = 0; ks < 2; ++ks) {
      s8v af[MFR], bf_[4];
      #pragma unroll
      for (int mf = 0; mf < MFR; ++mf) {
        int row = wm + mf * 16 + colc;
        int kby = (ks * 64 + rowg * 16) ^ ((row & 7) << 4);
        af[mf] = *(const s8v*)((const char*)Ab + row * 128 + kby);
      }
      #pragma unroll
      for (int nf = 0; nf < 4; ++nf) {
        int row = wn + nf * 16 + colc;
        int kby = (ks * 64 + rowg * 16) ^ ((row & 7) << 4);
        bf_[nf] = *(const s8v*)((const char*)Bb + row * 128 + kby);
      }
      __builtin_amdgcn_s_setprio(1);
      #pragma unroll
      for (int mf = 0; mf < MFR; ++mf)
        #pragma unroll
        for (int nf = 0; nf < 4; ++nf)
          acc[mf][nf] = mfma16(af[mf], bf_[nf], acc[mf][nf]);
      __builtin_amdgcn_s_setprio(0);
    }
  };

  STAGE(0, AsmA, BsmA);
  for (int kb = 0; kb < 1024; kb += 128) {
    STAGE(kb + 64, AsmB, BsmB);
    if constexpr (TM == 128) WAIT_VMCNT(8); else WAIT_VMCNT(6);
    SBAR();
    COMPUTE(AsmA, BsmA);
    SBAR();
    if (kb + 128 < 1024) {
      STAGE(kb + 128, AsmA, BsmA);
      if constexpr (TM == 128) WAIT_VMCNT(8); else WAIT_VMCNT(6);
    } else {
      WAIT_VMCNT(0);
    }
    SBAR();
    COMPUTE(AsmB, BsmB);
    SBAR();
  }

  if (MODE == 0) {
    int c = (int)(col0 >> 10);   // 0=q 1=k 2=v (tiles never straddle)
    #pragma unroll
    for (int mf = 0; mf < MFR; ++mf) {
      int m0 = (int)row0 + wm + mf * 16 + rowg * 4;
      int bb = m0 >> 10, l0 = m0 & 1023;   // l0 % 4 == 0, 4 consecutive l
      #pragma unroll
      for (int nf = 0; nf < 4; ++nf) {
        int n = (int)col0 + wn + nf * 16 + colc;
        int hh = (n >> 6) & 15, hd = n & 63;
        int bhl = bb * 16 + hh;
        if (c == 2) {
          ushort4 h4;
          h4.x = f2bfn(acc[mf][nf][0]);
          h4.y = f2bfn(acc[mf][nf][1]);
          h4.z = f2bfn(acc[mf][nf][2]);
          h4.w = f2bfn(acc[mf][nf][3]);
          *(ushort4*)(vxo + ((size_t)bhl * 64 + hd) * 1024 + l0) = h4;
        } else {
          unsigned short* dst = ((c == 0) ? qxo : kxo) +
                                ((size_t)bhl * 1024 + l0) * 64 + hd;
          float sc_ = (c == 0) ? QSCALE_ : 1.0f;
          #pragma unroll
          for (int r = 0; r < 4; ++r)
            dst[(size_t)r * 64] = f2bfn(acc[mf][nf][r] * sc_);
        }
      }
    }
  } else {
    #pragma unroll
    for (int mf = 0; mf < MFR; ++mf) {
      #pragma unroll
      for (int r = 0; r < 4; ++r) {
        int m = (int)row0 + wm + mf * 16 + rowg * 4 + r;
        #pragma unroll
        for (int nf = 0; nf < 4; ++nf) {
          int n = (int)col0 + wn + nf * 16 + colc;
          out[(size_t)m * 1024 + n] = acc[mf][nf][r] + bias[n];
        }
      }
    }
  }
}

// ---------------------------------------------------------------------------
// attn_flash v10: v9 + deferred lsum reduction (per-lane partial through the
// loop; single cross-lane reduce in the epilogue — valid since rescale factor
// is uniform across the 4 lanes of each row).
// ---------------------------------------------------------------------------
__global__ __launch_bounds__(512) void attn_flash(
    const unsigned short* __restrict__ qx, const unsigned short* __restrict__ kx,
    const unsigned short* __restrict__ vx, const int* __restrict__ meta,
    unsigned short* __restrict__ ao) {
  int n = blockIdx.x;                    // 512 blocks: 64 bh x 8 qt2
  int bh = ((n & 7) << 3) | (n >> 6);    // XCD swizzle (bijective)
  int qt2 = (n >> 3) & 7;
  int b = bh >> 4, h = bh & 15;
  const int* mb = meta + b * 8;
  if (mb[4]) return;  // sparse regime -> attn_sparse owns this batch
  int t00 = mb[0], t10 = mb[1];

  int tid = threadIdx.x, lane = tid & 63, wv = tid >> 6;
  int g = lane >> 4, colc = lane & 15;
  int bq0 = qt2 * 128;
  int q0 = bq0 + wv * 16;

  if (!t10) {
    // self-only: out row = v row (cold path; vx is transposed [d][l])
    #pragma unroll
    for (int it = 0; it < 4; ++it) {
      int idx = tid + it * 512;
      int r = idx >> 4, dc = (idx & 15) * 4;
      ushort4 o;
      unsigned short* op = (unsigned short*)&o;
      #pragma unroll
      for (int j = 0; j < 4; ++j)
        op[j] = vx[((size_t)bh * 64 + dc + j) * 1024 + bq0 + r];
      *(ushort4*)(ao + ((size_t)b * 1024 + bq0 + r) * 1024 + h * 64 + dc) = o;
    }
    return;
  }
  bool local_only = !t00;

  __shared__ __align__(16) unsigned short KsmA[128 * 64];   // 128 j x 64 d
  __shared__ __align__(16) unsigned short KsmB[128 * 64];
  __shared__ __align__(16) unsigned short VsmA[64 * 128];   // 64 d x 128 j
  __shared__ __align__(16) unsigned short VsmB[64 * 128];
  __shared__ __align__(16) unsigned short px[8][16][64];    // per-wave, reused

  // Q fragments (B operand: row=i=colc, 2 k-steps cover K=64)
  const unsigned short* qb = qx + ((size_t)bh * 1024 + q0 + colc) * 64 + g * 8;
  s8v Q0 = *(const s8v*)(qb);
  s8v Q1 = *(const s8v*)(qb + 32);

  f4v O[4];
  #pragma unroll
  for (int df = 0; df < 4; ++df) O[df] = (f4v){0.f, 0.f, 0.f, 0.f};
  float m = -1e30f, lsum = 0.f;   // per-lane partial (reduced at epilogue)

  const unsigned short* kxb = kx + ((size_t)bh << 10) * 64;
  const unsigned short* vxb = vx + ((size_t)bh << 16);

  int jt_lo = 0, jt_hi = 7;
  if (local_only) {
    int lo = (bq0 - 16) >> 7, hi = (bq0 + 143) >> 7;
    jt_lo = lo < 0 ? 0 : lo;
    jt_hi = hi > 7 ? 7 : hi;
  }

  auto STAGE = [&](int jt, unsigned short* Kd, unsigned short* Vd) {
    int jc = jt << 7;
    #pragma unroll
    for (int p = 0; p < 2; ++p) {
      int cidx = p * 512 + tid;
      // K: 128 rows x 128B (8 chunks/row)
      int krow = cidx >> 3;
      int ksc = (cidx & 7) ^ (krow & 7);
      gload16(kxb + (size_t)(jc + krow) * 64 + ksc * 8,
              Kd + (size_t)(p * 512 + wv * 64) * 8);
      // V: 64 d-rows x 256B (16 chunks/row)
      int vrow = cidx >> 4;
      int vsc = (cidx & 15) ^ (vrow & 15);
      gload16(vxb + (size_t)vrow * 1024 + jc + vsc * 8,
              Vd + (size_t)(p * 512 + wv * 64) * 8);
    }
  };

  int swk = (colc & 7) << 4;       // K read swizzle (j-row & 7 == colc & 7)
  int swv = colc << 4;             // V read swizzle (d-row & 15 == colc)
  int sx = (colc & 7) << 1;        // px slot swizzle

  auto COMPUTE = [&](int jc0, const char* Kb, const char* Vb) {
    if (local_only && (jc0 + 127 < q0 - 16 || jc0 > q0 + 31)) return;
    // ---- S^T: s[jf][r] = S[j=jc0+jf*16+4g+r][i=q0+colc], jf=0..7 ----
    f4v s[8];
    __builtin_amdgcn_s_setprio(1);
    #pragma unroll
    for (int jf = 0; jf < 8; ++jf) {
      const char* kp = Kb + (jf * 16 + colc) * 128;
      s8v K0 = *(const s8v*)(kp + ((g * 16) ^ swk));
      s8v K1 = *(const s8v*)(kp + ((64 + g * 16) ^ swk));
      f4v acc = (f4v){0.f, 0.f, 0.f, 0.f};
      acc = mfma16(K0, Q0, acc);
      acc = mfma16(K1, Q1, acc);
      s[jf] = acc;
    }
    __builtin_amdgcn_s_setprio(0);

    if (local_only) {
      int i = q0 + colc;
      #pragma unroll
      for (int jf = 0; jf < 8; ++jf)
        #pragma unroll
        for (int r = 0; r < 4; ++r) {
          int j = jc0 + jf * 16 + 4 * g + r;
          int dj = i - j;
          if (dj > 16 || dj < -16) s[jf][r] = -1e30f;
        }
    }

    // ---- per-row (per-lane) chunk max over 32 values ----
    float cm = -1e30f;
    #pragma unroll
    for (int jf = 0; jf < 8; ++jf)
      #pragma unroll
      for (int r = 0; r < 4; ++r) cm = fmaxf(cm, s[jf][r]);
    cm = fmaxf(cm, __shfl_xor(cm, 16, 64));
    cm = fmaxf(cm, __shfl_xor(cm, 32, 64));

    // T13 defer-rescale (fac uniform across the 4 lanes of each row)
    if (__any(cm > m + 8.0f)) {
      float mn = fmaxf(m, cm);
      float fac = __builtin_amdgcn_exp2f(m - mn);
      m = mn;
      lsum *= fac;
      float fo[4];
      #pragma unroll
      for (int r = 0; r < 4; ++r)
        fo[r] = __shfl(fac, (lane & 48) + g * 4 + r, 64);
      #pragma unroll
      for (int df = 0; df < 4; ++df)
        #pragma unroll
        for (int r = 0; r < 4; ++r) O[df][r] *= fo[r];
    }

    // ---- two 64-j halves: P -> px (wave-private) -> PV ----
    #pragma unroll
    for (int hf = 0; hf < 2; ++hf) {
      #pragma unroll
      for (int j4 = 0; j4 < 4; ++j4) {
        int jf = hf * 4 + j4;
        float p0 = __builtin_amdgcn_exp2f(s[jf][0] - m);
        float p1 = __builtin_amdgcn_exp2f(s[jf][1] - m);
        float p2 = __builtin_amdgcn_exp2f(s[jf][2] - m);
        float p3 = __builtin_amdgcn_exp2f(s[jf][3] - m);
        lsum += (p0 + p1) + (p2 + p3);
        ushort4 pk;
        pk.x = f2bfn(p0); pk.y = f2bfn(p1); pk.z = f2bfn(p2); pk.w = f2bfn(p3);
        *(ushort4*)&px[wv][colc][4 * ((j4 * 4 + g) ^ sx)] = pk;
      }
      s8v Pf[2];
      #pragma unroll
      for (int ks = 0; ks < 2; ++ks)
        Pf[ks] = *(const s8v*)&px[wv][colc][4 * ((ks * 8 + 2 * g) ^ sx)];
      __builtin_amdgcn_s_setprio(1);
      #pragma unroll
      for (int df = 0; df < 4; ++df) {
        const char* vp = Vb + (df * 16 + colc) * 256;
        #pragma unroll
        for (int ks = 0; ks < 2; ++ks) {
          s8v Vf = *(const s8v*)(vp + ((hf * 128 + ks * 64 + g * 16) ^ swv));
          O[df] = mfma16(Pf[ks], Vf, O[df]);
        }
      }
      __builtin_amdgcn_s_setprio(0);
    }
  };

  STAGE(jt_lo, KsmA, VsmA);
  int jt = jt_lo;
  while (true) {
    if (jt + 1 <= jt_hi) { STAGE(jt + 1, KsmB, VsmB); WAIT_VMCNT(4); }
    else                 { WAIT_VMCNT(0); }
    SBAR();
    COMPUTE(jt << 7, (const char*)KsmA, (const char*)VsmA);
    SBAR();
    if (++jt > jt_hi) break;
    if (jt + 1 <= jt_hi) { STAGE(jt + 1, KsmA, VsmA); WAIT_VMCNT(4); }
    else                 { WAIT_VMCNT(0); }
    SBAR();
    COMPUTE(jt << 7, (const char*)KsmB, (const char*)VsmB);
    SBAR();
    if (++jt > jt_hi) break;
  }

  // ---- epilogue: single cross-lane lsum reduction, then normalize ----
  lsum += __shfl_xor(lsum, 16, 64);
  lsum += __shfl_xor(lsum, 32, 64);
  float linv[4];
  #pragma unroll
  for (int r = 0; r < 4; ++r)
    linv[r] = 1.0f / __shfl(lsum, (lane & 48) + g * 4 + r, 64);
  #pragma unroll
  for (int df = 0; df < 4; ++df) {
    #pragma unroll
    for (int r = 0; r < 4; ++r) {
      int i = q0 + g * 4 + r;
      ao[((size_t)b * 1024 + i) * 1024 + h * 64 + df * 16 + colc] =
          f2bfn(O[df][r] * linv[r]);
    }
  }
}

// ---------------------------------------------------------------------------
// attn_sparse: top-k regime fallback (cold at runtime).
// ---------------------------------------------------------------------------
__global__ __launch_bounds__(256) void attn_sparse(
    const unsigned short* __restrict__ qx, const unsigned short* __restrict__ kx,
    const unsigned short* __restrict__ vx, const int* __restrict__ meta,
    unsigned short* __restrict__ ao) {
  __shared__ float S[32][1028];
  __shared__ float qs[32][68];
  __shared__ float kc[64][68];
  __shared__ float rowsum_s[32];

  int tid = threadIdx.x;
  int lane = tid & 63;
  int wv = tid >> 6;
  int id = blockIdx.x;
  int rt = id & 31;
  int h = (id >> 5) & 15;
  int b = id >> 9;
  int bh = b * 16 + h;
  int row0 = rt * 32;

  const int* mb = meta + b * 8;
  int t00 = mb[0], t10 = mb[1], t01 = mb[2], t11 = mb[3], needs = mb[4];
  if (!needs) return;

  #pragma unroll
  for (int i = 0; i < 8; ++i) {
    int idx = tid + 256 * i;
    int r = idx >> 6, d = idx & 63;
    qs[r][d] = bf2f(qx[((size_t)bh * 1024 + row0 + r) * 64 + d]);
  }

  int lr = lane >> 4, lc = lane & 15;
  int r_a = wv * 8 + lr * 2;
  int r_b = r_a + 1;

  for (int cb = 0; cb < 16; ++cb) {
    __syncthreads();
    #pragma unroll
    for (int i = 0; i < 2; ++i) {
      int idx = tid + 256 * i;
      int cc = idx >> 3, d0 = (idx & 7) * 8;
      union { s8v v; unsigned short u[8]; } kv8;
      kv8.v = *(const s8v*)(kx + ((size_t)bh * 1024 + cb * 64 + cc) * 64 + d0);
      #pragma unroll
      for (int j = 0; j < 8; ++j) kc[cc][d0 + j] = bf2f(kv8.u[j]);
    }
    __syncthreads();

    float acc0[4] = {0.f, 0.f, 0.f, 0.f};
    float acc1[4] = {0.f, 0.f, 0.f, 0.f};
    for (int dq = 0; dq < 64; dq += 4) {
      float4 qa = *(const float4*)&qs[r_a][dq];
      float4 qb = *(const float4*)&qs[r_b][dq];
      #pragma unroll
      for (int cj = 0; cj < 4; ++cj) {
        float4 kv = *(const float4*)&kc[lc + 16 * cj][dq];
        acc0[cj] += qa.x * kv.x + qa.y * kv.y + qa.z * kv.z + qa.w * kv.w;
        acc1[cj] += qb.x * kv.x + qb.y * kv.y + qb.z * kv.z + qb.w * kv.w;
      }
    }
    #pragma unroll
    for (int cj = 0; cj < 4; ++cj) {
      S[r_a][cb * 64 + lc + 16 * cj] = acc0[cj] * LN2_;
      S[r_b][cb * 64 + lc + 16 * cj] = acc1[cj] * LN2_;
    }
  }

  for (int rr = 0; rr < 8; ++rr) {
    int r = wv * 8 + rr;
    int grow = row0 + r;
    float sv[16];
    unsigned kv[16];
    #pragma unroll
    for (int i2 = 0; i2 < 16; ++i2) {
      float s = S[r][lane + 64 * i2];
      sv[i2] = s;
      unsigned u = __float_as_uint(s);
      kv[i2] = (u & 0x80000000u) ? ~u : (u | 0x80000000u);
    }
    unsigned T = 0u;
    for (int bit = 31; bit >= 0; --bit) {
      unsigned cand = T | (1u << bit);
      int cnt = 0;
      #pragma unroll
      for (int i2 = 0; i2 < 16; ++i2) cnt += (kv[i2] >= cand) ? 1 : 0;
      for (int off = 32; off; off >>= 1) cnt += __shfl_xor(cnt, off, 64);
      if (cnt >= KTOP_) T = cand;
    }
    float mx = -INFINITY;
    int kept = 0;
    unsigned kmask = 0;
    #pragma unroll
    for (int i2 = 0; i2 < 16; ++i2) {
      int j = lane + 64 * i2;
      int sp = (kv[i2] >= T) ? 1 : 0;
      int dj = grow - j;
      int lo = (dj <= 16 && dj >= -16) ? 1 : 0;
      int keep = sp ? (lo ? t11 : t01) : (lo ? t10 : t00);
      kept += keep;
      if (keep) { kmask |= (1u << i2); mx = fmaxf(mx, sv[i2]); }
    }
    for (int off = 32; off; off >>= 1) {
      mx = fmaxf(mx, __shfl_xor(mx, off, 64));
      kept += __shfl_xor(kept, off, 64);
    }
    if (kept == 0) {
      #pragma unroll
      for (int i2 = 0; i2 < 16; ++i2) {
        int j = lane + 64 * i2;
        S[r][j] = (j == grow) ? 1.0f : 0.0f;
      }
      if (lane == 0) rowsum_s[r] = 1.0f;
    } else {
      float sum = 0.f;
      #pragma unroll
      for (int i2 = 0; i2 < 16; ++i2) {
        float p = ((kmask >> i2) & 1u) ? __expf(sv[i2] - mx) : 0.0f;
        sum += p;
        S[r][lane + 64 * i2] = p;
      }
      for (int off = 32; off; off >>= 1) sum += __shfl_xor(sum, off, 64);
      if (lane == 0) rowsum_s[r] = sum;
    }
  }

  int ld = lane & 15;
  int d0 = ld * 4;
  float4 oa0 = make_float4(0.f, 0.f, 0.f, 0.f);
  float4 oa1 = make_float4(0.f, 0.f, 0.f, 0.f);
  for (int vb = 0; vb < 16; ++vb) {
    __syncthreads();
    #pragma unroll
    for (int i = 0; i < 2; ++i) {
      int idx = tid + 256 * i;
      int d = idx >> 3, c0 = (idx & 7) * 8;
      union { s8v v; unsigned short u[8]; } vv8;
      vv8.v = *(const s8v*)(vx + ((size_t)bh * 64 + d) * 1024 + vb * 64 + c0);
      #pragma unroll
      for (int j = 0; j < 8; ++j) kc[c0 + j][d] = bf2f(vv8.u[j]);
    }
    __syncthreads();
    for (int cq = 0; cq < 64; cq += 4) {
      float4 pa = *(const float4*)&S[r_a][vb * 64 + cq];
      float4 pb = *(const float4*)&S[r_b][vb * 64 + cq];
      float par[4] = {pa.x, pa.y, pa.z, pa.w};
      float pbr[4] = {pb.x, pb.y, pb.z, pb.w};
      #pragma unroll
      for (int tt = 0; tt < 4; ++tt) {
        float4 vv = *(const float4*)&kc[cq + tt][d0];
        oa0.x += par[tt] * vv.x; oa0.y += par[tt] * vv.y;
        oa0.z += par[tt] * vv.z; oa0.w += par[tt] * vv.w;
        oa1.x += pbr[tt] * vv.x; oa1.y += pbr[tt] * vv.y;
        oa1.z += pbr[tt] * vv.z; oa1.w += pbr[tt] * vv.w;
      }
    }
  }
  float inv0 = 1.0f / rowsum_s[r_a];
  float inv1 = 1.0f / rowsum_s[r_b];
  ushort4 o0, o1;
  unsigned short* o0p = (unsigned short*)&o0;
  unsigned short* o1p = (unsigned short*)&o1;
  float v0[4] = {oa0.x * inv0, oa0.y * inv0, oa0.z * inv0, oa0.w * inv0};
  float v1[4] = {oa1.x * inv1, oa1.y * inv1, oa1.z * inv1, oa1.w * inv1};
  #pragma unroll
  for (int j = 0; j < 4; ++j) {
    o0p[j] = f2bf(v0[j]);
    o1p[j] = f2bf(v1[j]);
  }
  *(ushort4*)(ao + ((size_t)b * 1024 + row0 + r_a) * 1024 + h * 64 + d0) = o0;
  *(ushort4*)(ao + ((size_t)b * 1024 + row0 + r_b) * 1024 + h * 64 + d0) = o1;
}

// ---------------------------------------------------------------------------
// Fallback f32 kernels (small-ws force path only)
// ---------------------------------------------------------------------------
__global__ __launch_bounds__(256) void pool_kernel(const float* __restrict__ x,
                                                   float* __restrict__ pooled) {
  int g = blockIdx.x * 256 + threadIdx.x;
  int b = g >> 10, d = g & 1023;
  const float* xp = x + ((size_t)b << 20) + d;
  float s = 0.f, m = -INFINITY;
  #pragma unroll 4
  for (int l = 0; l < 1024; ++l) {
    float v = xp[(size_t)l << 10];
    s += v;
    m = fmaxf(m, v);
  }
  pooled[g] = (s * (1.0f / 1024.0f) + m) * 0.5f;
}

__global__ __launch_bounds__(256) void qkv_gemm(const float* __restrict__ X,
                                                const float* __restrict__ W,
                                                float* __restrict__ qw,
                                                float* __restrict__ kw,
                                                float* __restrict__ vw) {
  __shared__ float As[8][128];
  __shared__ float Bs[8][128];
  int tid = threadIdx.x;
  int row0 = blockIdx.y * 128, col0 = blockIdx.x * 128;
  int lr = tid >> 1;
  int lk = (tid & 1) * 4;
  int ty = tid >> 4, tx = tid & 15;
  float acc[8][8] = {};

  for (int kb = 0; kb < 1024; kb += 8) {
    float4 a4 = *(const float4*)(X + (size_t)(row0 + lr) * 1024 + kb + lk);
    float4 b4 = *(const float4*)(W + (size_t)(col0 + lr) * 1024 + kb + lk);
    __syncthreads();
    As[lk + 0][lr] = a4.x; As[lk + 1][lr] = a4.y; As[lk + 2][lr] = a4.z; As[lk + 3][lr] = a4.w;
    Bs[lk + 0][lr] = b4.x; Bs[lk + 1][lr] = b4.y; Bs[lk + 2][lr] = b4.z; Bs[lk + 3][lr] = b4.w;
    __syncthreads();
    #pragma unroll
    for (int kk = 0; kk < 8; ++kk) {
      float av[8], bv[8];
      #pragma unroll
      for (int i = 0; i < 8; ++i) av[i] = As[kk][ty * 8 + i];
      #pragma unroll
      for (int j = 0; j < 8; ++j) bv[j] = Bs[kk][tx * 8 + j];
      #pragma unroll
      for (int i = 0; i < 8; ++i)
        #pragma unroll
        for (int j = 0; j < 8; ++j) acc[i][j] += av[i] * bv[j];
    }
  }
  #pragma unroll
  for (int i = 0; i < 8; ++i) {
    int m = row0 + ty * 8 + i;
    int bb = m >> 10, l = m & 1023;
    #pragma unroll
    for (int j = 0; j < 8; j += 4) {
      int n = col0 + tx * 8 + j;
      int c = n >> 10;
      int hh = (n >> 6) & 15;
      int hd = n & 63;
      float* base = (c == 0) ? qw : (c == 1) ? kw : vw;
      float* dst = base + ((size_t)(bb * 16 + hh) * 1024 + l) * 64 + hd;
      *(float4*)dst = make_float4(acc[i][j], acc[i][j + 1], acc[i][j + 2], acc[i][j + 3]);
    }
  }
}

__global__ __launch_bounds__(256) void proj_gemm(const float* __restrict__ A,
                                                 const float* __restrict__ W,
                                                 const float* __restrict__ bias,
                                                 float* __restrict__ out) {
  __shared__ float As[8][128];
  __shared__ float Bs[8][128];
  int tid = threadIdx.x;
  int row0 = blockIdx.y * 128, col0 = blockIdx.x * 128;
  int lr = tid >> 1;
  int lk = (tid & 1) * 4;
  int ty = tid >> 4, tx = tid & 15;
  float acc[8][8] = {};

  for (int kb = 0; kb < 1024; kb += 8) {
    float4 a4 = *(const float4*)(A + (size_t)(row0 + lr) * 1024 + kb + lk);
    float4 b4 = *(const float4*)(W + (size_t)(col0 + lr) * 1024 + kb + lk);
    __syncthreads();
    As[lk + 0][lr] = a4.x; As[lk + 1][lr] = a4.y; As[lk + 2][lr] = a4.z; As[lk + 3][lr] = a4.w;
    Bs[lk + 0][lr] = b4.x; Bs[lk + 1][lr] = b4.y; Bs[lk + 2][lr] = b4.z; Bs[lk + 3][lr] = b4.w;
    __syncthreads();
    #pragma unroll
    for (int kk = 0; kk < 8; ++kk) {
      float av[8], bv[8];
      #pragma unroll
      for (int i = 0; i < 8; ++i) av[i] = As[kk][ty * 8 + i];
      #pragma unroll
      for (int j = 0; j < 8; ++j) bv[j] = Bs[kk][tx * 8 + j];
      #pragma unroll
      for (int i = 0; i < 8; ++i)
        #pragma unroll
        for (int j = 0; j < 8; ++j) acc[i][j] += av[i] * bv[j];
    }
  }
  #pragma unroll
  for (int i = 0; i < 8; ++i) {
    int m = row0 + ty * 8 + i;
    #pragma unroll
    for (int j = 0; j < 8; j += 4) {
      int n = col0 + tx * 8 + j;
      *(float4*)(out + (size_t)m * 1024 + n) =
          make_float4(acc[i][j] + bias[n], acc[i][j + 1] + bias[n + 1],
                      acc[i][j + 2] + bias[n + 2], acc[i][j + 3] + bias[n + 3]);
    }
  }
}

__global__ __launch_bounds__(256) void pattern_kernel(
    const float* __restrict__ pooled,
    const float* __restrict__ w1, const float* __restrict__ b1,
    const float* __restrict__ lng, const float* __restrict__ lnb,
    const float* __restrict__ w2, const float* __restrict__ b2,
    const float* __restrict__ w3, const float* __restrict__ b3,
    const float* __restrict__ pb, int* __restrict__ meta) {
  __shared__ float pool_s[1024];
  __shared__ float h1[1024];
  __shared__ float h2[512];
  __shared__ float red[256];
  int b = blockIdx.x, t = threadIdx.x;

  for (int i = t; i < 1024; i += 256) pool_s[i] = pooled[b * 1024 + i];
  __syncthreads();
  for (int o = t; o < 1024; o += 256) {
    float acc = b1[o];
    const float* wr = w1 + (size_t)o * 1024;
    for (int k = 0; k < 1024; ++k) acc += pool_s[k] * wr[k];
    h1[o] = acc;
  }
  __syncthreads();
  float ls = 0.f;
  for (int i = t; i < 1024; i += 256) ls += h1[i];
  red[t] = ls; __syncthreads();
  for (int s = 128; s > 0; s >>= 1) { if (t < s) red[t] += red[t + s]; __syncthreads(); }
  float mean = red[0] * (1.0f / 1024.0f);
  __syncthreads();
  float lq = 0.f;
  for (int i = t; i < 1024; i += 256) { float dv = h1[i] - mean; lq += dv * dv; }
  red[t] = lq; __syncthreads();
  for (int s = 128; s > 0; s >>= 1) { if (t < s) red[t] += red[t + s]; __syncthreads(); }
  float var = red[0] * (1.0f / 1024.0f);
  float rstd = 1.0f / sqrtf(var + 1e-5f);
  __syncthreads();
  for (int i = t; i < 1024; i += 256) {
    float v = (h1[i] - mean) * rstd * lng[i] + lnb[i];
    h1[i] = 0.5f * v * (1.0f + erff(v * 0.70710678118654752f));
  }
  __syncthreads();
  for (int o = t; o < 512; o += 256) {
    float acc = b2[o];
    const float* wr = w2 + (size_t)o * 1024;
    for (int k = 0; k < 1024; ++k) acc += h1[k] * wr[k];
    h2[o] = 0.5f * acc * (1.0f + erff(acc * 0.70710678118654752f));
  }
  __syncthreads();
  float lgv[3];
  for (int c = 0; c < 3; ++c) {
    float p = 0.f;
    for (int i = t; i < 512; i += 256) p += h2[i] * w3[c * 512 + i];
    __syncthreads();
    red[t] = p; __syncthreads();
    for (int s = 128; s > 0; s >>= 1) { if (t < s) red[t] += red[t + s]; __syncthreads(); }
    lgv[c] = red[0] + b3[c] + pb[c];
  }
  if (t == 0) {
    float mx = fmaxf(lgv[0], fmaxf(lgv[1], lgv[2]));
    float e0 = __expf(lgv[0] - mx), e1 = __expf(lgv[1] - mx), e2 = __expf(lgv[2] - mx);
    float inv = 1.0f / (e0 + e1 + e2);
    float p0 = e0 * inv, p1 = e1 * inv, p2 = e2 * inv;
    float c00 = p1;
    float c10 = p0 + p1;
    float c01 = p1 + p2;
    float c11 = (p0 + p1) + p2;
    int t00 = c00 > 0.1f, t10 = c10 > 0.1f, t01 = c01 > 0.1f, t11 = c11 > 0.1f;
    meta[b * 8 + 0] = t00;
    meta[b * 8 + 1] = t10;
    meta[b * 8 + 2] = t01;
    meta[b * 8 + 3] = t11;
    meta[b * 8 + 4] = (t00 != t01) || (t10 != t11);
  }
}

__global__ __launch_bounds__(256) void attn_kernel_f32(const float* __restrict__ qw,
                                                       const float* __restrict__ kw,
                                                       const float* __restrict__ vw,
                                                       const int* __restrict__ meta,
                                                       float* __restrict__ ao) {
  __shared__ float S[32][1028];
  __shared__ float qs[32][68];
  __shared__ float kc[64][68];
  __shared__ float rowsum_s[32];

  int tid = threadIdx.x;
  int lane = tid & 63;
  int wv = tid >> 6;
  int id = blockIdx.x;
  int rt = id & 31;
  int h = (id >> 5) & 15;
  int b = id >> 9;
  int bh = b * 16 + h;
  int row0 = rt * 32;

  const int* mb = meta + b * 8;
  int t00 = mb[0], t10 = mb[1], t01 = mb[2], t11 = mb[3], needs = mb[4];

  {
    const float4* qp = (const float4*)(qw + ((size_t)bh * 1024 + row0 + wv * 8) * 64);
    #pragma unroll
    for (int i = 0; i < 2; ++i) {
      int f = lane + 64 * i;
      float4 v = qp[f];
      int r = wv * 8 + (f >> 4);
      int d = (f & 15) << 2;
      qs[r][d] = v.x; qs[r][d + 1] = v.y; qs[r][d + 2] = v.z; qs[r][d + 3] = v.w;
    }
  }

  int lr = lane >> 4, lc = lane & 15;
  int r_a = wv * 8 + lr * 2;
  int r_b = r_a + 1;

  for (int cb = 0; cb < 16; ++cb) {
    __syncthreads();
    const float4* kp = (const float4*)(kw + ((size_t)bh * 1024 + cb * 64) * 64);
    #pragma unroll
    for (int i = 0; i < 4; ++i) {
      int f = tid + 256 * i;
      float4 v = kp[f];
      int c = f >> 4, d = (f & 15) << 2;
      kc[c][d] = v.x; kc[c][d + 1] = v.y; kc[c][d + 2] = v.z; kc[c][d + 3] = v.w;
    }
    __syncthreads();

    float acc0[4] = {0.f, 0.f, 0.f, 0.f};
    float acc1[4] = {0.f, 0.f, 0.f, 0.f};
    for (int dq = 0; dq < 64; dq += 4) {
      float4 qa = *(const float4*)&qs[r_a][dq];
      float4 qb = *(const float4*)&qs[r_b][dq];
      #pragma unroll
      for (int cj = 0; cj < 4; ++cj) {
        float4 kv = *(const float4*)&kc[lc + 16 * cj][dq];
        acc0[cj] += qa.x * kv.x + qa.y * kv.y + qa.z * kv.z + qa.w * kv.w;
        acc1[cj] += qb.x * kv.x + qb.y * kv.y + qb.z * kv.z + qb.w * kv.w;
      }
    }
    #pragma unroll
    for (int cj = 0; cj < 4; ++cj) {
      S[r_a][cb * 64 + lc + 16 * cj] = acc0[cj] * SCALE_;
      S[r_b][cb * 64 + lc + 16 * cj] = acc1[cj] * SCALE_;
    }
  }

  for (int rr = 0; rr < 8; ++rr) {
    int r = wv * 8 + rr;
    int grow = row0 + r;
    float sv[16];
    unsigned kv[16];
    #pragma unroll
    for (int i2 = 0; i2 < 16; ++i2) {
      float s = S[r][lane + 64 * i2];
      sv[i2] = s;
      unsigned u = __float_as_uint(s);
      kv[i2] = (u & 0x80000000u) ? ~u : (u | 0x80000000u);
    }
    unsigned T = 0u;
    if (needs) {
      for (int bit = 31; bit >= 0; --bit) {
        unsigned cand = T | (1u << bit);
        int cnt = 0;
        #pragma unroll
        for (int i2 = 0; i2 < 16; ++i2) cnt += (kv[i2] >= cand) ? 1 : 0;
        for (int off = 32; off; off >>= 1) cnt += __shfl_xor(cnt, off, 64);
        if (cnt >= KTOP_) T = cand;
      }
    }
    float mx = -INFINITY;
    int kept = 0;
    unsigned kmask = 0;
    #pragma unroll
    for (int i2 = 0; i2 < 16; ++i2) {
      int j = lane + 64 * i2;
      int sp = (kv[i2] >= T) ? 1 : 0;
      int dj = grow - j;
      int lo = (dj <= 16 && dj >= -16) ? 1 : 0;
      int keep = sp ? (lo ? t11 : t01) : (lo ? t10 : t00);
      kept += keep;
      if (keep) { kmask |= (1u << i2); mx = fmaxf(mx, sv[i2]); }
    }
    for (int off = 32; off; off >>= 1) {
      mx = fmaxf(mx, __shfl_xor(mx, off, 64));
      kept += __shfl_xor(kept, off, 64);
    }
    if (kept == 0) {
      #pragma unroll
      for (int i2 = 0; i2 < 16; ++i2) {
        int j = lane + 64 * i2;
        S[r][j] = (j == grow) ? 1.0f : 0.0f;
      }
      if (lane == 0) rowsum_s[r] = 1.0f;
    } else {
      float sum = 0.f;
      #pragma unroll
      for (int i2 = 0; i2 < 16; ++i2) {
        float p = ((kmask >> i2) & 1u) ? __expf(sv[i2] - mx) : 0.0f;
        sum += p;
        S[r][lane + 64 * i2] = p;
      }
      for (int off = 32; off; off >>= 1) sum += __shfl_xor(sum, off, 64);
      if (lane == 0) rowsum_s[r] = sum;
    }
  }

  int ld = lane & 15;
  int d0 = ld * 4;
  float4 oa0 = make_float4(0.f, 0.f, 0.f, 0.f);
  float4 oa1 = make_float4(0.f, 0.f, 0.f, 0.f);
  for (int vb = 0; vb < 16; ++vb) {
    __syncthreads();
    const float4* vp = (const float4*)(vw + ((size_t)bh * 1024 + vb * 64) * 64);
    #pragma unroll
    for (int i = 0; i < 4; ++i) {
      int f = tid + 256 * i;
      float4 v = vp[f];
      int c = f >> 4, d = (f & 15) << 2;
      kc[c][d] = v.x; kc[c][d + 1] = v.y; kc[c][d + 2] = v.z; kc[c][d + 3] = v.w;
    }
    __syncthreads();
    for (int cq = 0; cq < 64; cq += 4) {
      float4 pa = *(const float4*)&S[r_a][vb * 64 + cq];
      float4 pb = *(const float4*)&S[r_b][vb * 64 + cq];
      float par[4] = {pa.x, pa.y, pa.z, pa.w};
      float pbr[4] = {pb.x, pb.y, pb.z, pb.w};
      #pragma unroll
      for (int tt = 0; tt < 4; ++tt) {
        float4 vv = *(const float4*)&kc[cq + tt][d0];
        oa0.x += par[tt] * vv.x; oa0.y += par[tt] * vv.y;
        oa0.z += par[tt] * vv.z; oa0.w += par[tt] * vv.w;
        oa1.x += pbr[tt] * vv.x; oa1.y += pbr[tt] * vv.y;
        oa1.z += pbr[tt] * vv.z; oa1.w += pbr[tt] * vv.w;
      }
    }
  }
  float inv0 = 1.0f / rowsum_s[r_a];
  float inv1 = 1.0f / rowsum_s[r_b];
  float* p0 = ao + ((size_t)b * 1024 + row0 + r_a) * 1024 + h * 64 + d0;
  float* p1 = ao + ((size_t)b * 1024 + row0 + r_b) * 1024 + h * 64 + d0;
  *(float4*)p0 = make_float4(oa0.x * inv0, oa0.y * inv0, oa0.z * inv0, oa0.w * inv0);
  *(float4*)p1 = make_float4(oa1.x * inv1, oa1.y * inv1, oa1.z * inv1, oa1.w * inv1);
}

// ---------------------------------------------------------------------------
extern "C" void kernel_launch(void* const* d_in, const int* in_sizes, int n_in,
                              void* d_out, int out_size, void* d_ws, size_t ws_size,
                              hipStream_t stream) {
  const float* x      = (const float*)d_in[0];
  const float* w_qkv  = (const float*)d_in[1];
  const float* w_proj = (const float*)d_in[2];
  const float* b_proj = (const float*)d_in[3];
  const float* ps_w1  = (const float*)d_in[4];
  const float* ps_b1  = (const float*)d_in[5];
  const float* ln_g   = (const float*)d_in[6];
  const float* ln_b   = (const float*)d_in[7];
  const float* ps_w2  = (const float*)d_in[8];
  const float* ps_b2  = (const float*)d_in[9];
  const float* ps_w3  = (const float*)d_in[10];
  const float* ps_b3  = (const float*)d_in[11];
  const float* pbias  = (const float*)d_in[12];
  // d_in[13]=sparse_w, d_in[14]=sparse_b: monotone per-row affine -> top-k invariant.

  float* ws = (float*)d_ws;
  float* pooled = ws;                              // 4096 (force path)
  int*   meta   = (int*)(ws + 4096);               // 32
  float* h1buf  = ws + 8192;                       // 4096
  float* h2buf  = ws + 12288;                      // 2048
  float* ppsum  = ws + 16384;                      // 262144
  float* ppmax  = ws + 278528;                     // 262144
  float* qw = ws + 1048576;                        // 4M each (force path)
  float* kw = qw + 4194304;
  float* vw = kw + 4194304;
  float* ao = vw + 4194304;
  unsigned short* u16b = (unsigned short*)(ao + 4194304);
  unsigned short* xs   = u16b;                     // [4096][1024]   4.19M u16
  unsigned short* wqs  = xs + 4194304;             // [3072][1024]   3.15M
  unsigned short* wps  = wqs + 3145728;            // [1024][1024]   1.05M
  unsigned short* aos  = wps + 1048576;            // [4096][1024]   4.19M
  unsigned short* qx   = aos + 4194304;            // [64][1024][64] 4.19M
  unsigned short* kx   = qx + 4194304;             // 4.19M
  unsigned short* vx   = kx + 4194304;             // [64][64][1024] 4.19M
  float* out = (float*)d_out;

  const size_t NEED_FULL = (size_t)(1048576 + 4 * 4194304) * 4 +
                           (size_t)(4194304 + 3145728 + 1048576 + 4194304 +
                                    3 * 4194304) * 2;

  if (ws_size >= NEED_FULL) {
    pool1<<<4352, 256, 0, stream>>>(x, ppsum, ppmax, xs, w_qkv, w_proj, wqs, wps);
    ps_gemv1<<<64, 256, 0, stream>>>(ppsum, ppmax, ps_w1, ps_b1, h1buf);
    ps_gemv2<<<32, 256, 0, stream>>>(h1buf, ln_g, ln_b, ps_w2, ps_b2, h2buf);
    ps_logits<<<4, 256, 0, stream>>>(h2buf, ps_w3, ps_b3, pbias, meta);

    gemm_sp<0, 128><<<768, 256, 0, stream>>>(xs, wqs, nullptr, qx, kx, vx,
                                             nullptr, 24);

    attn_flash<<<512, 512, 0, stream>>>(qx, kx, vx, meta, aos);
    attn_sparse<<<2048, 256, 0, stream>>>(qx, kx, vx, meta, aos);

    gemm_sp<1, 64><<<512, 256, 0, stream>>>(aos, wps, b_proj,
                                            nullptr, nullptr, nullptr, out, 8);
  } else {
    // fallback: f32 path (needs only the f32 region)
    pool_kernel<<<16, 256, 0, stream>>>(x, pooled);
    pattern_kernel<<<4, 256, 0, stream>>>(pooled, ps_w1, ps_b1, ln_g, ln_b,
                                          ps_w2, ps_b2, ps_w3, ps_b3, pbias, meta);
    qkv_gemm<<<dim3(24, 32), 256, 0, stream>>>(x, w_qkv, qw, kw, vw);
    attn_kernel_f32<<<2048, 256, 0, stream>>>(qw, kw, vw, meta, ao);
    proj_gemm<<<dim3(8, 32), 256, 0, stream>>>(ao, w_proj, b_proj, out);
  }
}